// Round 19
// baseline (204.276 us; speedup 1.0000x reference)
//
#include <hip/hip_runtime.h>

typedef float f32x4 __attribute__((ext_vector_type(4)));
typedef short bf16x8 __attribute__((ext_vector_type(8)));

__device__ inline unsigned short f2bf(float f) {
    unsigned int u = __builtin_bit_cast(unsigned int, f);
    unsigned int r = (u + 0x7FFFu + ((u >> 16) & 1u)) >> 16;
    return (unsigned short)r;
}
__device__ inline float bf2f(unsigned short u) {
    unsigned int x = ((unsigned int)u) << 16;
    return __builtin_bit_cast(float, x);
}
__device__ inline float f4get(const float4& v, int e) {
    return e == 0 ? v.x : (e == 1 ? v.y : (e == 2 ? v.z : v.w));
}

// ---------------- Combined prep: tok->bf16 | W transpose->bf16 | carr split-K partials
__global__ __launch_bounds__(256) void k_prep(const float* __restrict__ tok,
                                              const float* __restrict__ W,
                                              const float* __restrict__ dep,
                                              const float* __restrict__ idx,
                                              const float* __restrict__ bvec,
                                              unsigned short* __restrict__ tokbf,
                                              unsigned short* __restrict__ WTbf,
                                              float* __restrict__ carrp) {
    __shared__ float s_tile[64][65];
    int bx = blockIdx.x;
    if (bx < 256) {
        int i = bx * 256 + threadIdx.x;
        const float4 v = *(const float4*)(tok + (long)i * 4);
        ushort4 o;
        o.x = f2bf(v.x); o.y = f2bf(v.y); o.z = f2bf(v.z); o.w = f2bf(v.w);
        *(ushort4*)(tokbf + (long)i * 4) = o;
    } else if (bx < 304) {
        int bb = bx - 256;
        int sec = bb >> 4;
        int tt = bb & 15;
        int k0 = (tt >> 2) * 64, j0 = (tt & 3) * 64;
        int tx = threadIdx.x & 63, ty = threadIdx.x >> 6;
#pragma unroll
        for (int r = 0; r < 16; r++) {
            int kk = ty * 16 + r;
            s_tile[kk][tx] = W[(sec * 256 + k0 + kk) * 256 + j0 + tx];
        }
        __syncthreads();
#pragma unroll
        for (int r = 0; r < 16; r++) {
            int jj = ty * 16 + r;
            WTbf[(sec * 256 + j0 + jj) * 256 + k0 + tx] = f2bf(s_tile[tx][jj]);
        }
    } else {
        int q = bx - 304;
        int d = q >> 3;
        int c = q & 7;
        int j = threadIdx.x;
        float acc = (c == 0) ? bvec[j] : 0.f;
        int kbeg = c * 32, kend = kbeg + 32;
#pragma unroll 4
        for (int k = kbeg; k < kend; k++) {
            float dv = dep[(d + 1) * 256 + k];
            acc += dv * (W[(768 + k) * 256 + j] + W[(1280 + k) * 256 + j]);
            acc += idx[k] * W[(1024 + k) * 256 + j];
            acc += idx[256 + k] * W[(1536 + k) * 256 + j];
        }
        if (d == 13) {
#pragma unroll 4
            for (int k = kbeg; k < kend; k++) {
                float dv = dep[14 * 256 + k];
                acc += dv * (W[(256 + k) * 256 + j] + W[(512 + k) * 256 + j]);
            }
        }
        carrp[(long)q * 256 + j] = acc;
    }
}

// ---------------- carr reduce
__global__ __launch_bounds__(256) void k_carrsum(const float* __restrict__ carrp,
                                                 float* __restrict__ carr) {
    int d = blockIdx.x;
    int j = threadIdx.x;
    float s = 0.f;
#pragma unroll
    for (int c = 0; c < 8; c++) s += carrp[(long)(d * 8 + c) * 256 + j];
    carr[d * 256 + j] = s;
}

// ---------------- T tables via MFMA (bf16 out)
__global__ __launch_bounds__(256) void k_ttmm(const unsigned short* __restrict__ tokbf,
                                              const unsigned short* __restrict__ WTbf,
                                              unsigned short* __restrict__ T) {
    int wid = threadIdx.x >> 6, lane = threadIdx.x & 63;
    int l15 = lane & 15, l4 = lane >> 4;
    int row0 = blockIdx.x * 32;
    int sec = blockIdx.y;

    f32x4 acc[2][4] = {};
    for (int kk = 0; kk < 8; kk++) {
        int k0 = kk * 32 + l4 * 8;
        bf16x8 af[2], bfr[4];
#pragma unroll
        for (int mi = 0; mi < 2; mi++)
            af[mi] = *(const bf16x8*)(tokbf + (long)(row0 + mi * 16 + l15) * 256 + k0);
#pragma unroll
        for (int ni = 0; ni < 4; ni++)
            bfr[ni] = *(const bf16x8*)(WTbf + (long)(sec * 256 + wid * 64 + ni * 16 + l15) * 256 + k0);
#pragma unroll
        for (int mi = 0; mi < 2; mi++)
#pragma unroll
            for (int ni = 0; ni < 4; ni++)
                acc[mi][ni] = __builtin_amdgcn_mfma_f32_16x16x32_bf16(af[mi], bfr[ni],
                                                                     acc[mi][ni], 0, 0, 0);
    }
#pragma unroll
    for (int mi = 0; mi < 2; mi++)
#pragma unroll
        for (int r = 0; r < 4; r++) {
            int row = row0 + mi * 16 + l4 * 4 + r;
#pragma unroll
            for (int ni = 0; ni < 4; ni++) {
                int c = wid * 64 + ni * 16 + l15;
                T[(long)sec * 262144 + (long)row * 256 + c] = f2bf(acc[mi][ni][r]);
            }
        }
}

// ---------------- Fused levels 13..8 at S=32. 256 blocks, 512 threads, 8 waves x 32 cols.
// NO breg (spill-bound at 512 threads): bfr loaded per kstep from L2-resident WTbf.
__global__ __attribute__((amdgpu_waves_per_eu(2, 2))) __launch_bounds__(512)
void k_big(const int* __restrict__ leaf_ids,
           const int* __restrict__ op_ids,
           const unsigned short* __restrict__ T,
           const float* __restrict__ carr,
           const float* __restrict__ gamma,
           const float* __restrict__ beta,
           const unsigned short* __restrict__ WTbf,
           unsigned short* __restrict__ outbuf) {
    __shared__ unsigned short sA[128 * 256];
    __shared__ unsigned short sB[128 * 256];
    __shared__ int s_nid13[128];
    __shared__ int s_leaf[256];
    __shared__ float s_part[8][64][2];
    int b = blockIdx.x >> 5;
    int q = blockIdx.x & 31;
    int t = threadIdx.x;
    int wid = t >> 6, lane = t & 63;
    int l15 = lane & 15, l4 = lane >> 4;
    const unsigned short* T0 = T;
    const unsigned short* T1 = T + 262144;
    const unsigned short* T2 = T + 524288;

    float gv[2], bv[2];
#pragma unroll
    for (int ni = 0; ni < 2; ni++) {
        int c = wid * 32 + ni * 16 + l15;
        gv[ni] = gamma[c];
        bv[ni] = beta[c];
    }

    // ---- Phases A/B: level-13 gather (128 nodes) + level-12 GEMM (64 rows) each
#pragma unroll 1
    for (int h = 0; h < 2; h++) {
        if (t < 128) s_nid13[t] = op_ids[b * 16383 + 8191 + q * 256 + h * 128 + t];
        if (t < 256) s_leaf[t] = leaf_ids[b * 16384 + q * 512 + h * 256 + t];
        __syncthreads();

        {
            const float* c13 = carr + 13 * 256;
            float4 dd[4], g4[4], b4[4];
#pragma unroll
            for (int q2 = 0; q2 < 4; q2++) {
                int c0 = l15 * 16 + q2 * 4;
                dd[q2] = *(const float4*)(c13 + c0);
                g4[q2] = *(const float4*)(gamma + c0);
                b4[q2] = *(const float4*)(beta + c0);
            }
#pragma unroll
            for (int j = 0; j < 4; j++) {
                int node = wid * 16 + j * 4 + l4;
                int nid = s_nid13[node];
                int ll = s_leaf[2 * node], lr = s_leaf[2 * node + 1];
                bf16x8 a0 = *(const bf16x8*)(T0 + (long)nid * 256 + l15 * 16);
                bf16x8 a1 = *(const bf16x8*)(T0 + (long)nid * 256 + l15 * 16 + 8);
                bf16x8 b0 = *(const bf16x8*)(T1 + (long)ll * 256 + l15 * 16);
                bf16x8 b1 = *(const bf16x8*)(T1 + (long)ll * 256 + l15 * 16 + 8);
                bf16x8 c0 = *(const bf16x8*)(T2 + (long)lr * 256 + l15 * 16);
                bf16x8 c1 = *(const bf16x8*)(T2 + (long)lr * 256 + l15 * 16 + 8);
                float v[16];
                float s = 0.f, s2 = 0.f;
#pragma unroll
                for (int e = 0; e < 8; e++) {
                    float x = bf2f((unsigned short)a0[e]) + bf2f((unsigned short)b0[e]) +
                              bf2f((unsigned short)c0[e]) + f4get(dd[e >> 2], e & 3);
                    x = fmaxf(x, 0.f);
                    v[e] = x;
                    s += x;
                    s2 += x * x;
                }
#pragma unroll
                for (int e = 0; e < 8; e++) {
                    float x = bf2f((unsigned short)a1[e]) + bf2f((unsigned short)b1[e]) +
                              bf2f((unsigned short)c1[e]) + f4get(dd[2 + (e >> 2)], e & 3);
                    x = fmaxf(x, 0.f);
                    v[8 + e] = x;
                    s += x;
                    s2 += x * x;
                }
#pragma unroll
                for (int m = 1; m < 16; m <<= 1) {
                    s += __shfl_xor(s, m);
                    s2 += __shfl_xor(s2, m);
                }
                float mu = s * (1.f / 256.f);
                float rs = rsqrtf(s2 * (1.f / 256.f) - mu * mu + 1e-5f);
                int swz = ((node >> 1) & 7) << 4;
                bf16x8 o0, o1;
#pragma unroll
                for (int e = 0; e < 8; e++) {
                    o0[e] = (short)f2bf((v[e] - mu) * rs * f4get(g4[e >> 2], e & 3) +
                                        f4get(b4[e >> 2], e & 3));
                    o1[e] = (short)f2bf((v[8 + e] - mu) * rs * f4get(g4[2 + (e >> 2)], e & 3) +
                                        f4get(b4[2 + (e >> 2)], e & 3));
                }
                *(bf16x8*)((char*)sA + node * 512 + ((l15 * 32) ^ swz)) = o0;
                *(bf16x8*)((char*)sA + node * 512 + ((l15 * 32 + 16) ^ swz)) = o1;
            }
        }
        __syncthreads();

        // level-12 GEMM: 64 rows from 128 nodes in sA
        float tv[4][4][2];
#pragma unroll
        for (int mi = 0; mi < 4; mi++)
#pragma unroll
            for (int r = 0; r < 4; r++) {
                int row = mi * 16 + l4 * 4 + r;
                int nid = op_ids[b * 16383 + 4095 + q * 128 + h * 64 + row];
#pragma unroll
                for (int ni = 0; ni < 2; ni++)
                    tv[mi][r][ni] = bf2f(T0[(long)nid * 256 + wid * 32 + ni * 16 + l15]);
            }

        f32x4 acc[4][2] = {};
        for (int kk = 0; kk < 16; kk++) {
            int k0 = kk * 32 + l4 * 8;
            int hi = k0 >> 8;
            int innerk = k0 & 255;
            int binr = (k0 & 255) * 2;
            bf16x8 af[4], bfr[2];
#pragma unroll
            for (int mi = 0; mi < 4; mi++) {
                int node = 2 * (mi * 16 + l15) + hi;
                af[mi] = *(const bf16x8*)((const char*)sA + node * 512 +
                                          (binr ^ (((node >> 1) & 7) << 4)));
            }
            const unsigned short* Wb = WTbf + (long)(256 + hi * 256) * 256;
#pragma unroll
            for (int ni = 0; ni < 2; ni++) {
                int cn = wid * 32 + ni * 16 + l15;
                bfr[ni] = *(const bf16x8*)(Wb + (long)cn * 256 + innerk);
            }
#pragma unroll
            for (int mi = 0; mi < 4; mi++)
#pragma unroll
                for (int ni = 0; ni < 2; ni++)
                    acc[mi][ni] = __builtin_amdgcn_mfma_f32_16x16x32_bf16(af[mi], bfr[ni],
                                                                         acc[mi][ni], 0, 0, 0);
        }

        const float* carr12 = carr + 12 * 256;
        float cv[2];
#pragma unroll
        for (int ni = 0; ni < 2; ni++) cv[ni] = carr12[wid * 32 + ni * 16 + l15];

#pragma unroll
        for (int mi = 0; mi < 4; mi++)
#pragma unroll
            for (int r = 0; r < 4; r++) {
                float s = 0.f, s2 = 0.f;
#pragma unroll
                for (int ni = 0; ni < 2; ni++) {
                    float hh = fmaxf(acc[mi][ni][r] + tv[mi][r][ni] + cv[ni], 0.f);
                    acc[mi][ni][r] = hh;
                    s += hh;
                    s2 += hh * hh;
                }
#pragma unroll
                for (int m2 = 1; m2 < 16; m2 <<= 1) {
                    s += __shfl_xor(s, m2);
                    s2 += __shfl_xor(s2, m2);
                }
                if (l15 == 0) {
                    int row = mi * 16 + l4 * 4 + r;
                    s_part[wid][row][0] = s;
                    s_part[wid][row][1] = s2;
                }
            }
        __syncthreads();

#pragma unroll
        for (int mi = 0; mi < 4; mi++)
#pragma unroll
            for (int r = 0; r < 4; r++) {
                int row = mi * 16 + l4 * 4 + r;
                float s = 0.f, s2 = 0.f;
#pragma unroll
                for (int w = 0; w < 8; w++) {
                    s += s_part[w][row][0];
                    s2 += s_part[w][row][1];
                }
                float mu = s * (1.f / 256.f);
                float rs = rsqrtf(s2 * (1.f / 256.f) - mu * mu + 1e-5f);
                int hrow = h * 64 + row;
#pragma unroll
                for (int ni = 0; ni < 2; ni++) {
                    int c = wid * 32 + ni * 16 + l15;
                    *(unsigned short*)((char*)sB + hrow * 512 +
                                       ((c * 2) ^ (((hrow >> 1) & 7) << 4))) =
                        f2bf((acc[mi][ni][r] - mu) * rs * gv[ni] + bv[ni]);
                }
            }
        __syncthreads();
    }

    // ---- Levels 11..8: LDS ping-pong, cur = sB (128 rows)
    unsigned short* cur = sB;
    unsigned short* nxt = sA;
    for (int ld = 11; ld >= 8; ld--) {
        int ng = 1 << ld;
        int m = ng >> 5;            // 64, 32, 16, 8
        int mtiles = (m + 15) >> 4; // 4, 2, 1, 1

        float tv[4][4][2];
#pragma unroll
        for (int mi = 0; mi < 4; mi++)
            if (mi < mtiles)
#pragma unroll
                for (int r = 0; r < 4; r++) {
                    int row = mi * 16 + l4 * 4 + r;
                    int rc = row < m ? row : m - 1;
                    int nid = op_ids[b * 16383 + (ng - 1) + q * m + rc];
#pragma unroll
                    for (int ni = 0; ni < 2; ni++)
                        tv[mi][r][ni] = bf2f(T0[(long)nid * 256 + wid * 32 + ni * 16 + l15]);
                }

        f32x4 acc[4][2] = {};
        for (int kk = 0; kk < 16; kk++) {
            int k0 = kk * 32 + l4 * 8;
            int hi = k0 >> 8;
            int innerk = k0 & 255;
            int binr = (k0 & 255) * 2;
            bf16x8 af[4], bfr[2];
#pragma unroll
            for (int mi = 0; mi < 4; mi++)
                if (mi < mtiles) {
                    int node = 2 * (mi * 16 + l15) + hi;
                    af[mi] = *(const bf16x8*)((const char*)cur + node * 512 +
                                              (binr ^ (((node >> 1) & 7) << 4)));
                }
            const unsigned short* Wb = WTbf + (long)(256 + hi * 256) * 256;
#pragma unroll
            for (int ni = 0; ni < 2; ni++) {
                int cn = wid * 32 + ni * 16 + l15;
                bfr[ni] = *(const bf16x8*)(Wb + (long)cn * 256 + innerk);
            }
#pragma unroll
            for (int mi = 0; mi < 4; mi++)
                if (mi < mtiles)
#pragma unroll
                    for (int ni = 0; ni < 2; ni++)
                        acc[mi][ni] = __builtin_amdgcn_mfma_f32_16x16x32_bf16(
                            af[mi], bfr[ni], acc[mi][ni], 0, 0, 0);
        }

        const float* carr_d = carr + ld * 256;
        float cv[2];
#pragma unroll
        for (int ni = 0; ni < 2; ni++) cv[ni] = carr_d[wid * 32 + ni * 16 + l15];

#pragma unroll
        for (int mi = 0; mi < 4; mi++)
            if (mi < mtiles)
#pragma unroll
                for (int r = 0; r < 4; r++) {
                    float s = 0.f, s2 = 0.f;
#pragma unroll
                    for (int ni = 0; ni < 2; ni++) {
                        float hh = fmaxf(acc[mi][ni][r] + tv[mi][r][ni] + cv[ni], 0.f);
                        acc[mi][ni][r] = hh;
                        s += hh;
                        s2 += hh * hh;
                    }
#pragma unroll
                    for (int m2 = 1; m2 < 16; m2 <<= 1) {
                        s += __shfl_xor(s, m2);
                        s2 += __shfl_xor(s2, m2);
                    }
                    if (l15 == 0) {
                        int row = mi * 16 + l4 * 4 + r;
                        s_part[wid][row][0] = s;
                        s_part[wid][row][1] = s2;
                    }
                }
        __syncthreads();

#pragma unroll
        for (int mi = 0; mi < 4; mi++)
            if (mi < mtiles)
#pragma unroll
                for (int r = 0; r < 4; r++) {
                    int row = mi * 16 + l4 * 4 + r;
                    if (row < m) {
                        float s = 0.f, s2 = 0.f;
#pragma unroll
                        for (int w = 0; w < 8; w++) {
                            s += s_part[w][row][0];
                            s2 += s_part[w][row][1];
                        }
                        float mu = s * (1.f / 256.f);
                        float rs = rsqrtf(s2 * (1.f / 256.f) - mu * mu + 1e-5f);
#pragma unroll
                        for (int ni = 0; ni < 2; ni++) {
                            int c = wid * 32 + ni * 16 + l15;
                            float val = (acc[mi][ni][r] - mu) * rs * gv[ni] + bv[ni];
                            if (ld == 8) {
                                outbuf[((long)b * 256 + q * 8 + row) * 256 + c] = f2bf(val);
                            } else {
                                *(unsigned short*)((char*)nxt + row * 512 +
                                                   ((c * 2) ^ (((row >> 1) & 7) << 4))) = f2bf(val);
                            }
                        }
                    }
                }
        __syncthreads();
        unsigned short* tmp = cur;
        cur = nxt;
        nxt = tmp;
    }
}

// ---------------- Subtree tail: levels 7..3 at S=8. 64 blocks, 512 threads, breg[16][2].
__global__ __attribute__((amdgpu_waves_per_eu(2, 2))) __launch_bounds__(512)
void k_tail(const unsigned short* __restrict__ prev,
            const int* __restrict__ op_ids,
            const unsigned short* __restrict__ T0,
            const float* __restrict__ carr,
            const float* __restrict__ gamma,
            const float* __restrict__ beta,
            const unsigned short* __restrict__ WTbf,
            unsigned short* __restrict__ mid) {
    __shared__ unsigned short sA[32 * 256];
    __shared__ unsigned short sB[32 * 256];
    __shared__ int s_nid_all[255];
    __shared__ float s_part[8][16][2];
    int b = blockIdx.x >> 3;
    int q = blockIdx.x & 7;
    int t = threadIdx.x;
    int wid = t >> 6, lane = t & 63;
    int l15 = lane & 15, l4 = lane >> 4;

    bf16x8 breg[16][2];
#pragma unroll
    for (int kk = 0; kk < 16; kk++) {
        int k0 = kk * 32 + l4 * 8;
        int hi = k0 >> 8;
        int innerk = k0 & 255;
        const unsigned short* Wb = WTbf + (long)(256 + hi * 256) * 256;
#pragma unroll
        for (int ni = 0; ni < 2; ni++) {
            int cn = wid * 32 + ni * 16 + l15;
            breg[kk][ni] = *(const bf16x8*)(Wb + (long)cn * 256 + innerk);
        }
    }

    if (t < 255) s_nid_all[t] = op_ids[b * 16383 + t];
    float gv[2], bv[2];
#pragma unroll
    for (int ni = 0; ni < 2; ni++) {
        int c = wid * 32 + ni * 16 + l15;
        gv[ni] = gamma[c];
        bv[ni] = beta[c];
    }
    __syncthreads();

    unsigned short* cur = sA;
    unsigned short* nxt = sB;

    for (int ld = 7; ld >= 3; ld--) {
        int ng = 1 << ld;
        int m = ng >> 3;

        float tv[4][2];
#pragma unroll
        for (int r = 0; r < 4; r++) {
            int row = l4 * 4 + r;
            int rc = row < m ? row : m - 1;
            int nid = s_nid_all[(ng - 1) + q * m + rc];
#pragma unroll
            for (int ni = 0; ni < 2; ni++)
                tv[r][ni] = bf2f(T0[(long)nid * 256 + wid * 32 + ni * 16 + l15]);
        }

        f32x4 acc[2] = {};
        if (ld == 7) {
            const unsigned short* X = prev + ((long)b * 256 + q * 32) * 256;
#pragma unroll
            for (int kk = 0; kk < 16; kk++) {
                int k0 = kk * 32 + l4 * 8;
                bf16x8 af = *(const bf16x8*)(X + (long)l15 * 512 + k0);
#pragma unroll
                for (int ni = 0; ni < 2; ni++)
                    acc[ni] = __builtin_amdgcn_mfma_f32_16x16x32_bf16(af, breg[kk][ni], acc[ni],
                                                                      0, 0, 0);
            }
        } else {
#pragma unroll
            for (int kk = 0; kk < 16; kk++) {
                int k0 = kk * 32 + l4 * 8;
                int hi = k0 >> 8;
                int binr = (k0 & 255) * 2;
                int node = 2 * l15 + hi;
                bf16x8 af = *(const bf16x8*)((const char*)cur + node * 512 +
                                             (binr ^ (((node >> 1) & 7) << 4)));
#pragma unroll
                for (int ni = 0; ni < 2; ni++)
                    acc[ni] = __builtin_amdgcn_mfma_f32_16x16x32_bf16(af, breg[kk][ni], acc[ni],
                                                                      0, 0, 0);
            }
        }

        const float* carr_d = carr + ld * 256;
        float cv[2];
#pragma unroll
        for (int ni = 0; ni < 2; ni++) cv[ni] = carr_d[wid * 32 + ni * 16 + l15];

#pragma unroll
        for (int r = 0; r < 4; r++) {
            float s = 0.f, s2 = 0.f;
#pragma unroll
            for (int ni = 0; ni < 2; ni++) {
                float hh = fmaxf(acc[ni][r] + tv[r][ni] + cv[ni], 0.f);
                acc[ni][r] = hh;
                s += hh;
                s2 += hh * hh;
            }
#pragma unroll
            for (int m2 = 1; m2 < 16; m2 <<= 1) {
                s += __shfl_xor(s, m2);
                s2 += __shfl_xor(s2, m2);
            }
            if (l15 == 0) {
                int row = l4 * 4 + r;
                s_part[wid][row][0] = s;
                s_part[wid][row][1] = s2;
            }
        }
        __syncthreads();

#pragma unroll
        for (int r = 0; r < 4; r++) {
            int row = l4 * 4 + r;
            if (row < m) {
                float s = 0.f, s2 = 0.f;
#pragma unroll
                for (int w = 0; w < 8; w++) {
                    s += s_part[w][row][0];
                    s2 += s_part[w][row][1];
                }
                float mu = s * (1.f / 256.f);
                float rs = rsqrtf(s2 * (1.f / 256.f) - mu * mu + 1e-5f);
#pragma unroll
                for (int ni = 0; ni < 2; ni++) {
                    int c = wid * 32 + ni * 16 + l15;
                    float val = (acc[ni][r] - mu) * rs * gv[ni] + bv[ni];
                    if (ld == 3) {
                        mid[(long)(b * 8 + q) * 256 + c] = f2bf(val);
                    } else {
                        *(unsigned short*)((char*)nxt + row * 512 +
                                           ((c * 2) ^ (((row >> 1) & 7) << 4))) = f2bf(val);
                    }
                }
            }
        }
        __syncthreads();
        unsigned short* tmp = cur;
        cur = nxt;
        nxt = tmp;
    }
}

// ---------------- Root: levels 2..0 in one block (256 threads, 4 waves x 64 cols).
__global__ __launch_bounds__(256) void k_root2(const unsigned short* __restrict__ mid,
                                               const int* __restrict__ op_ids,
                                               const unsigned short* __restrict__ T0,
                                               const float* __restrict__ carr,
                                               const float* __restrict__ gamma,
                                               const float* __restrict__ beta,
                                               const unsigned short* __restrict__ WTbf,
                                               float* __restrict__ out) {
    __shared__ unsigned short sL2[32 * 256];
    __shared__ unsigned short sL1[16 * 256];
    __shared__ float s_part[4][32][2];
    __shared__ int s_n2[32], s_n1[16], s_n0[8];
    int t = threadIdx.x;
    int wid = t >> 6, lane = t & 63;
    int l15 = lane & 15, l4 = lane >> 4;

    if (t < 32) s_n2[t] = op_ids[(t >> 2) * 16383 + 3 + (t & 3)];
    if (t < 16) s_n1[t] = op_ids[(t >> 1) * 16383 + 1 + (t & 1)];
    if (t < 8) s_n0[t] = op_ids[t * 16383];
    float gv[4], bv[4];
#pragma unroll
    for (int ni = 0; ni < 4; ni++) {
        int c = wid * 64 + ni * 16 + l15;
        gv[ni] = gamma[c];
        bv[ni] = beta[c];
    }
    __syncthreads();

    // ---- Level 2: 32 rows, A from mid
    {
        f32x4 acc[2][4] = {};
        for (int kk = 0; kk < 16; kk++) {
            int k0 = kk * 32 + l4 * 8;
            int hi = k0 >> 8;
            int innerk = k0 & 255;
            bf16x8 af[2], bfr[4];
#pragma unroll
            for (int mi = 0; mi < 2; mi++)
                af[mi] = *(const bf16x8*)(mid + (long)(mi * 16 + l15) * 512 + k0);
            const unsigned short* Wb = WTbf + (long)(256 + hi * 256) * 256;
#pragma unroll
            for (int ni = 0; ni < 4; ni++) {
                int cn = wid * 64 + ni * 16 + l15;
                bfr[ni] = *(const bf16x8*)(Wb + (long)cn * 256 + innerk);
            }
#pragma unroll
            for (int mi = 0; mi < 2; mi++)
#pragma unroll
                for (int ni = 0; ni < 4; ni++)
                    acc[mi][ni] = __builtin_amdgcn_mfma_f32_16x16x32_bf16(af[mi], bfr[ni],
                                                                         acc[mi][ni], 0, 0, 0);
        }
        const float* carr2 = carr + 2 * 256;
        float cv[4];
#pragma unroll
        for (int ni = 0; ni < 4; ni++) cv[ni] = carr2[wid * 64 + ni * 16 + l15];
#pragma unroll
        for (int mi = 0; mi < 2; mi++)
#pragma unroll
            for (int r = 0; r < 4; r++) {
                int row = mi * 16 + l4 * 4 + r;
                int nid = s_n2[row];
                float s = 0.f, s2 = 0.f;
#pragma unroll
                for (int ni = 0; ni < 4; ni++) {
                    int c = wid * 64 + ni * 16 + l15;
                    float h = fmaxf(acc[mi][ni][r] + bf2f(T0[(long)nid * 256 + c]) + cv[ni], 0.f);
                    acc[mi][ni][r] = h;
                    s += h;
                    s2 += h * h;
                }
#pragma unroll
                for (int m = 1; m < 16; m <<= 1) {
                    s += __shfl_xor(s, m);
                    s2 += __shfl_xor(s2, m);
                }
                if (l15 == 0) {
                    s_part[wid][row][0] = s;
                    s_part[wid][row][1] = s2;
                }
            }
        __syncthreads();
#pragma unroll
        for (int mi = 0; mi < 2; mi++)
#pragma unroll
            for (int r = 0; r < 4; r++) {
                int row = mi * 16 + l4 * 4 + r;
                float s = s_part[0][row][0] + s_part[1][row][0] + s_part[2][row][0] + s_part[3][row][0];
                float s2 = s_part[0][row][1] + s_part[1][row][1] + s_part[2][row][1] + s_part[3][row][1];
                float mu = s * (1.f / 256.f);
                float rs = rsqrtf(s2 * (1.f / 256.f) - mu * mu + 1e-5f);
#pragma unroll
                for (int ni = 0; ni < 4; ni++) {
                    int c = wid * 64 + ni * 16 + l15;
                    *(unsigned short*)((char*)sL2 + row * 512 +
                                       ((c * 2) ^ (((row >> 1) & 7) << 4))) =
                        f2bf((acc[mi][ni][r] - mu) * rs * gv[ni] + bv[ni]);
                }
            }
        __syncthreads();
    }

    // ---- Level 1: 16 rows
    {
        f32x4 acc[4] = {};
        for (int kk = 0; kk < 16; kk++) {
            int k0 = kk * 32 + l4 * 8;
            int hi = k0 >> 8;
            int innerk = k0 & 255;
            int binr = (k0 & 255) * 2;
            int node = 2 * l15 + hi;
            bf16x8 af = *(const bf16x8*)((const char*)sL2 + node * 512 +
                                         (binr ^ (((node >> 1) & 7) << 4)));
            const unsigned short* Wb = WTbf + (long)(256 + hi * 256) * 256;
#pragma unroll
            for (int ni = 0; ni < 4; ni++) {
                int cn = wid * 64 + ni * 16 + l15;
                bf16x8 bfr = *(const bf16x8*)(Wb + (long)cn * 256 + innerk);
                acc[ni] = __builtin_amdgcn_mfma_f32_16x16x32_bf16(af, bfr, acc[ni], 0, 0, 0);
            }
        }
        const float* carr1 = carr + 256;
        float cv[4];
#pragma unroll
        for (int ni = 0; ni < 4; ni++) cv[ni] = carr1[wid * 64 + ni * 16 + l15];
#pragma unroll
        for (int r = 0; r < 4; r++) {
            int row = l4 * 4 + r;
            int nid = s_n1[row];
            float s = 0.f, s2 = 0.f;
#pragma unroll
            for (int ni = 0; ni < 4; ni++) {
                int c = wid * 64 + ni * 16 + l15;
                float h = fmaxf(acc[ni][r] + bf2f(T0[(long)nid * 256 + c]) + cv[ni], 0.f);
                acc[ni][r] = h;
                s += h;
                s2 += h * h;
            }
#pragma unroll
            for (int m = 1; m < 16; m <<= 1) {
                s += __shfl_xor(s, m);
                s2 += __shfl_xor(s2, m);
            }
            if (l15 == 0) {
                s_part[wid][row][0] = s;
                s_part[wid][row][1] = s2;
            }
        }
        __syncthreads();
#pragma unroll
        for (int r = 0; r < 4; r++) {
            int row = l4 * 4 + r;
            float s = s_part[0][row][0] + s_part[1][row][0] + s_part[2][row][0] + s_part[3][row][0];
            float s2 = s_part[0][row][1] + s_part[1][row][1] + s_part[2][row][1] + s_part[3][row][1];
            float mu = s * (1.f / 256.f);
            float rs = rsqrtf(s2 * (1.f / 256.f) - mu * mu + 1e-5f);
#pragma unroll
            for (int ni = 0; ni < 4; ni++) {
                int c = wid * 64 + ni * 16 + l15;
                *(unsigned short*)((char*)sL1 + row * 512 +
                                   ((c * 2) ^ (((row >> 1) & 7) << 4))) =
                    f2bf((acc[ni][r] - mu) * rs * gv[ni] + bv[ni]);
            }
        }
        __syncthreads();
    }

    // ---- Level 0: 8 rows -> out
    {
        f32x4 acc[4] = {};
        for (int kk = 0; kk < 16; kk++) {
            int k0 = kk * 32 + l4 * 8;
            int hi = k0 >> 8;
            int innerk = k0 & 255;
            int binr = (k0 & 255) * 2;
            int node = 2 * (l15 & 7) + hi;
            bf16x8 af = *(const bf16x8*)((const char*)sL1 + node * 512 +
                                         (binr ^ (((node >> 1) & 7) << 4)));
            const unsigned short* Wb = WTbf + (long)(256 + hi * 256) * 256;
#pragma unroll
            for (int ni = 0; ni < 4; ni++) {
                int cn = wid * 64 + ni * 16 + l15;
                bf16x8 bfr = *(const bf16x8*)(Wb + (long)cn * 256 + innerk);
                acc[ni] = __builtin_amdgcn_mfma_f32_16x16x32_bf16(af, bfr, acc[ni], 0, 0, 0);
            }
        }
        float cv[4];
#pragma unroll
        for (int ni = 0; ni < 4; ni++) cv[ni] = carr[wid * 64 + ni * 16 + l15];
#pragma unroll
        for (int r = 0; r < 4; r++) {
            int row = l4 * 4 + r;
            int nid = s_n0[row & 7];
            float s = 0.f, s2 = 0.f;
#pragma unroll
            for (int ni = 0; ni < 4; ni++) {
                int c = wid * 64 + ni * 16 + l15;
                float h = fmaxf(acc[ni][r] + bf2f(T0[(long)nid * 256 + c]) + cv[ni], 0.f);
                acc[ni][r] = h;
                s += h;
                s2 += h * h;
            }
#pragma unroll
            for (int m = 1; m < 16; m <<= 1) {
                s += __shfl_xor(s, m);
                s2 += __shfl_xor(s2, m);
            }
            if (l15 == 0) {
                s_part[wid][row][0] = s;
                s_part[wid][row][1] = s2;
            }
        }
        __syncthreads();
#pragma unroll
        for (int r = 0; r < 4; r++) {
            int row = l4 * 4 + r;
            if (row < 8) {
                float s = s_part[0][row][0] + s_part[1][row][0] + s_part[2][row][0] + s_part[3][row][0];
                float s2 = s_part[0][row][1] + s_part[1][row][1] + s_part[2][row][1] + s_part[3][row][1];
                float mu = s * (1.f / 256.f);
                float rs = rsqrtf(s2 * (1.f / 256.f) - mu * mu + 1e-5f);
#pragma unroll
                for (int ni = 0; ni < 4; ni++) {
                    int c = wid * 64 + ni * 16 + l15;
                    out[row * 256 + c] = (acc[ni][r] - mu) * rs * gv[ni] + bv[ni];
                }
            }
        }
    }
}

extern "C" void kernel_launch(void* const* d_in, const int* in_sizes, int n_in,
                              void* d_out, int out_size, void* d_ws, size_t ws_size,
                              hipStream_t stream) {
    const int* leaf_ids = (const int*)d_in[0];
    const int* op_ids = (const int*)d_in[1];
    const float* tok = (const float*)d_in[2];
    const float* dep = (const float*)d_in[3];
    const float* idx = (const float*)d_in[4];
    const float* W = (const float*)d_in[5];
    const float* bvec = (const float*)d_in[6];
    const float* gamma = (const float*)d_in[7];
    const float* beta = (const float*)d_in[8];
    float* out = (float*)d_out;

    char* ws = (char*)d_ws;
    unsigned short* T = (unsigned short*)(ws);                            // 1.5 MB (bf16 T0|T1|T2)
    unsigned short* WTbf = (unsigned short*)(ws + 3u * 1024 * 1024);     // 384 KB
    unsigned short* tokbf = (unsigned short*)(ws + 3u * 1024 * 1024 + 512 * 1024);  // 512 KB
    float* carr = (float*)(ws + 4u * 1024 * 1024 + 64 * 1024);           // 14 KB
    float* carrp = (float*)(ws + 5u * 1024 * 1024);                      // 112 KB partials
    unsigned short* mid = (unsigned short*)(ws + 6u * 1024 * 1024);      // 32 KB (64x256 bf16)
    unsigned short* ebufB = (unsigned short*)(ws + 8u * 1024 * 1024);    // 1 MB (level-8 out)

    k_prep<<<416, 256, 0, stream>>>(tok, W, dep, idx, bvec, tokbf, WTbf, carrp);
    k_carrsum<<<14, 256, 0, stream>>>(carrp, carr);
    k_ttmm<<<dim3(32, 3), 256, 0, stream>>>(tokbf, WTbf, T);

    // levels 13..8 (256 blocks: batch x 1/32 subtree) -> ebufB (level-8 out, 256 rows/batch)
    k_big<<<256, 512, 0, stream>>>(leaf_ids, op_ids, T, carr, gamma, beta, WTbf, ebufB);
    // levels 7..3 (64 blocks: batch x eighth) -> mid (level-3 out, 8x256 per batch)
    k_tail<<<64, 512, 0, stream>>>(ebufB, op_ids, T, carr, gamma, beta, WTbf, mid);
    // levels 2..0
    k_root2<<<1, 256, 0, stream>>>(mid, op_ids, T, carr, gamma, beta, WTbf, out);
}

// Round 20
// 184.041 us; speedup vs baseline: 1.1100x; 1.1100x over previous
//
#include <hip/hip_runtime.h>

typedef float f32x4 __attribute__((ext_vector_type(4)));
typedef short bf16x8 __attribute__((ext_vector_type(8)));

__device__ inline unsigned short f2bf(float f) {
    unsigned int u = __builtin_bit_cast(unsigned int, f);
    unsigned int r = (u + 0x7FFFu + ((u >> 16) & 1u)) >> 16;
    return (unsigned short)r;
}
__device__ inline float bf2f(unsigned short u) {
    unsigned int x = ((unsigned int)u) << 16;
    return __builtin_bit_cast(float, x);
}
__device__ inline float f4get(const float4& v, int e) {
    return e == 0 ? v.x : (e == 1 ? v.y : (e == 2 ? v.z : v.w));
}

// ---------------- Combined prep: tok->bf16 | W transpose->bf16 | carr split-K partials
__global__ __launch_bounds__(256) void k_prep(const float* __restrict__ tok,
                                              const float* __restrict__ W,
                                              const float* __restrict__ dep,
                                              const float* __restrict__ idx,
                                              const float* __restrict__ bvec,
                                              unsigned short* __restrict__ tokbf,
                                              unsigned short* __restrict__ WTbf,
                                              float* __restrict__ carrp) {
    __shared__ float s_tile[64][65];
    int bx = blockIdx.x;
    if (bx < 256) {
        int i = bx * 256 + threadIdx.x;
        const float4 v = *(const float4*)(tok + (long)i * 4);
        ushort4 o;
        o.x = f2bf(v.x); o.y = f2bf(v.y); o.z = f2bf(v.z); o.w = f2bf(v.w);
        *(ushort4*)(tokbf + (long)i * 4) = o;
    } else if (bx < 304) {
        int bb = bx - 256;
        int sec = bb >> 4;
        int tt = bb & 15;
        int k0 = (tt >> 2) * 64, j0 = (tt & 3) * 64;
        int tx = threadIdx.x & 63, ty = threadIdx.x >> 6;
#pragma unroll
        for (int r = 0; r < 16; r++) {
            int kk = ty * 16 + r;
            s_tile[kk][tx] = W[(sec * 256 + k0 + kk) * 256 + j0 + tx];
        }
        __syncthreads();
#pragma unroll
        for (int r = 0; r < 16; r++) {
            int jj = ty * 16 + r;
            WTbf[(sec * 256 + j0 + jj) * 256 + k0 + tx] = f2bf(s_tile[tx][jj]);
        }
    } else {
        int q = bx - 304;
        int d = q >> 3;
        int c = q & 7;
        int j = threadIdx.x;
        float acc = (c == 0) ? bvec[j] : 0.f;
        int kbeg = c * 32, kend = kbeg + 32;
#pragma unroll 4
        for (int k = kbeg; k < kend; k++) {
            float dv = dep[(d + 1) * 256 + k];
            acc += dv * (W[(768 + k) * 256 + j] + W[(1280 + k) * 256 + j]);
            acc += idx[k] * W[(1024 + k) * 256 + j];
            acc += idx[256 + k] * W[(1536 + k) * 256 + j];
        }
        if (d == 13) {
#pragma unroll 4
            for (int k = kbeg; k < kend; k++) {
                float dv = dep[14 * 256 + k];
                acc += dv * (W[(256 + k) * 256 + j] + W[(512 + k) * 256 + j]);
            }
        }
        carrp[(long)q * 256 + j] = acc;
    }
}

// ---------------- carr reduce
__global__ __launch_bounds__(256) void k_carrsum(const float* __restrict__ carrp,
                                                 float* __restrict__ carr) {
    int d = blockIdx.x;
    int j = threadIdx.x;
    float s = 0.f;
#pragma unroll
    for (int c = 0; c < 8; c++) s += carrp[(long)(d * 8 + c) * 256 + j];
    carr[d * 256 + j] = s;
}

// ---------------- T tables via MFMA (bf16 out)
__global__ __launch_bounds__(256) void k_ttmm(const unsigned short* __restrict__ tokbf,
                                              const unsigned short* __restrict__ WTbf,
                                              unsigned short* __restrict__ T) {
    int wid = threadIdx.x >> 6, lane = threadIdx.x & 63;
    int l15 = lane & 15, l4 = lane >> 4;
    int row0 = blockIdx.x * 32;
    int sec = blockIdx.y;

    f32x4 acc[2][4] = {};
    for (int kk = 0; kk < 8; kk++) {
        int k0 = kk * 32 + l4 * 8;
        bf16x8 af[2], bfr[4];
#pragma unroll
        for (int mi = 0; mi < 2; mi++)
            af[mi] = *(const bf16x8*)(tokbf + (long)(row0 + mi * 16 + l15) * 256 + k0);
#pragma unroll
        for (int ni = 0; ni < 4; ni++)
            bfr[ni] = *(const bf16x8*)(WTbf + (long)(sec * 256 + wid * 64 + ni * 16 + l15) * 256 + k0);
#pragma unroll
        for (int mi = 0; mi < 2; mi++)
#pragma unroll
            for (int ni = 0; ni < 4; ni++)
                acc[mi][ni] = __builtin_amdgcn_mfma_f32_16x16x32_bf16(af[mi], bfr[ni],
                                                                     acc[mi][ni], 0, 0, 0);
    }
#pragma unroll
    for (int mi = 0; mi < 2; mi++)
#pragma unroll
        for (int r = 0; r < 4; r++) {
            int row = row0 + mi * 16 + l4 * 4 + r;
#pragma unroll
            for (int ni = 0; ni < 4; ni++) {
                int c = wid * 64 + ni * 16 + l15;
                T[(long)sec * 262144 + (long)row * 256 + c] = f2bf(acc[mi][ni][r]);
            }
        }
}

// ---------------- Fused level 13+12: gather = node-per-16-lanes, 16B table loads
__global__ __launch_bounds__(256) void k_level12f(const int* __restrict__ leaf_ids,
                                                  const int* __restrict__ op_ids,
                                                  const unsigned short* __restrict__ T,
                                                  const float* __restrict__ carr,
                                                  const float* __restrict__ gamma,
                                                  const float* __restrict__ beta,
                                                  const unsigned short* __restrict__ WTbf,
                                                  unsigned short* __restrict__ ebuf_out) {
    __shared__ unsigned short sA[64 * 256];
    __shared__ int s_nid13[64];
    __shared__ int s_leaf[128];
    __shared__ int s_nid[32];
    __shared__ float s_part[4][32][2];
    int b = blockIdx.y;
    int row0 = blockIdx.x * 32;
    int t = threadIdx.x;
    int wid = t >> 6, lane = t & 63;
    int l15 = lane & 15, l4 = lane >> 4;
    const unsigned short* T0 = T;
    const unsigned short* T1 = T + 262144;
    const unsigned short* T2 = T + 524288;

    if (t < 64) s_nid13[t] = op_ids[b * 16383 + 8191 + 2 * row0 + t];
    if (t < 128) s_leaf[t] = leaf_ids[b * 16384 + 4 * row0 + t];
    if (t < 32) s_nid[t] = op_ids[b * 16383 + 4095 + row0 + t];
    __syncthreads();

    {
        const float* c13 = carr + 13 * 256;
        float4 dd[4], g4[4], b4[4];
#pragma unroll
        for (int q = 0; q < 4; q++) {
            int c0 = l15 * 16 + q * 4;
            dd[q] = *(const float4*)(c13 + c0);
            g4[q] = *(const float4*)(gamma + c0);
            b4[q] = *(const float4*)(beta + c0);
        }
#pragma unroll
        for (int j = 0; j < 4; j++) {
            int node = wid * 16 + j * 4 + l4;
            int nid = s_nid13[node];
            int ll = s_leaf[2 * node], lr = s_leaf[2 * node + 1];
            bf16x8 a0 = *(const bf16x8*)(T0 + (long)nid * 256 + l15 * 16);
            bf16x8 a1 = *(const bf16x8*)(T0 + (long)nid * 256 + l15 * 16 + 8);
            bf16x8 b0 = *(const bf16x8*)(T1 + (long)ll * 256 + l15 * 16);
            bf16x8 b1 = *(const bf16x8*)(T1 + (long)ll * 256 + l15 * 16 + 8);
            bf16x8 c0 = *(const bf16x8*)(T2 + (long)lr * 256 + l15 * 16);
            bf16x8 c1 = *(const bf16x8*)(T2 + (long)lr * 256 + l15 * 16 + 8);
            float v[16];
            float s = 0.f, s2 = 0.f;
#pragma unroll
            for (int e = 0; e < 8; e++) {
                float x = bf2f((unsigned short)a0[e]) + bf2f((unsigned short)b0[e]) +
                          bf2f((unsigned short)c0[e]) + f4get(dd[e >> 2], e & 3);
                x = fmaxf(x, 0.f);
                v[e] = x;
                s += x;
                s2 += x * x;
            }
#pragma unroll
            for (int e = 0; e < 8; e++) {
                float x = bf2f((unsigned short)a1[e]) + bf2f((unsigned short)b1[e]) +
                          bf2f((unsigned short)c1[e]) + f4get(dd[2 + (e >> 2)], e & 3);
                x = fmaxf(x, 0.f);
                v[8 + e] = x;
                s += x;
                s2 += x * x;
            }
#pragma unroll
            for (int m = 1; m < 16; m <<= 1) {
                s += __shfl_xor(s, m);
                s2 += __shfl_xor(s2, m);
            }
            float mu = s * (1.f / 256.f);
            float rs = rsqrtf(s2 * (1.f / 256.f) - mu * mu + 1e-5f);
            int swz = ((node >> 1) & 7) << 4;
            bf16x8 o0, o1;
#pragma unroll
            for (int e = 0; e < 8; e++) {
                o0[e] = (short)f2bf((v[e] - mu) * rs * f4get(g4[e >> 2], e & 3) +
                                    f4get(b4[e >> 2], e & 3));
                o1[e] = (short)f2bf((v[8 + e] - mu) * rs * f4get(g4[2 + (e >> 2)], e & 3) +
                                    f4get(b4[2 + (e >> 2)], e & 3));
            }
            *(bf16x8*)((char*)sA + node * 512 + ((l15 * 32) ^ swz)) = o0;
            *(bf16x8*)((char*)sA + node * 512 + ((l15 * 32 + 16) ^ swz)) = o1;
        }
    }
    __syncthreads();

    f32x4 acc[2][4] = {};
    for (int kk = 0; kk < 16; kk++) {
        int k0 = kk * 32 + l4 * 8;
        int hi = k0 >> 8;
        int binr = (k0 & 255) * 2;
        bf16x8 af[2], bfr[4];
#pragma unroll
        for (int mi = 0; mi < 2; mi++) {
            int node = 2 * (mi * 16 + l15) + hi;
            af[mi] = *(const bf16x8*)((const char*)sA + node * 512 + (binr ^ (((node >> 1) & 7) << 4)));
        }
        const unsigned short* Wb = WTbf + (long)(256 + hi * 256) * 256;
        int innerk = k0 & 255;
#pragma unroll
        for (int ni = 0; ni < 4; ni++) {
            int cn = wid * 64 + ni * 16 + l15;
            bfr[ni] = *(const bf16x8*)(Wb + (long)cn * 256 + innerk);
        }
#pragma unroll
        for (int mi = 0; mi < 2; mi++)
#pragma unroll
            for (int ni = 0; ni < 4; ni++)
                acc[mi][ni] = __builtin_amdgcn_mfma_f32_16x16x32_bf16(af[mi], bfr[ni],
                                                                     acc[mi][ni], 0, 0, 0);
    }

    const float* carr_d = carr + 12 * 256;
    float cv[4], gv[4], bv[4];
#pragma unroll
    for (int ni = 0; ni < 4; ni++) {
        int c = wid * 64 + ni * 16 + l15;
        cv[ni] = carr_d[c];
        gv[ni] = gamma[c];
        bv[ni] = beta[c];
    }

#pragma unroll
    for (int mi = 0; mi < 2; mi++) {
#pragma unroll
        for (int r = 0; r < 4; r++) {
            int row = mi * 16 + l4 * 4 + r;
            int nid = s_nid[row];
            float s = 0.f, s2 = 0.f;
#pragma unroll
            for (int ni = 0; ni < 4; ni++) {
                int c = wid * 64 + ni * 16 + l15;
                float h = acc[mi][ni][r] + bf2f(T0[(long)nid * 256 + c]) + cv[ni];
                h = fmaxf(h, 0.f);
                acc[mi][ni][r] = h;
                s += h;
                s2 += h * h;
            }
#pragma unroll
            for (int m = 1; m < 16; m <<= 1) {
                s += __shfl_xor(s, m);
                s2 += __shfl_xor(s2, m);
            }
            if (l15 == 0) {
                s_part[wid][row][0] = s;
                s_part[wid][row][1] = s2;
            }
        }
    }
    __syncthreads();

#pragma unroll
    for (int mi = 0; mi < 2; mi++) {
#pragma unroll
        for (int r = 0; r < 4; r++) {
            int row = mi * 16 + l4 * 4 + r;
            float s = s_part[0][row][0] + s_part[1][row][0] + s_part[2][row][0] + s_part[3][row][0];
            float s2 = s_part[0][row][1] + s_part[1][row][1] + s_part[2][row][1] + s_part[3][row][1];
            float mu = s * (1.f / 256.f);
            float rs = rsqrtf(s2 * (1.f / 256.f) - mu * mu + 1e-5f);
            unsigned short* o = ebuf_out + ((long)b * 4096 + row0 + row) * 256;
#pragma unroll
            for (int ni = 0; ni < 4; ni++) {
                int c = wid * 64 + ni * 16 + l15;
                o[c] = f2bf((acc[mi][ni][r] - mu) * rs * gv[ni] + bv[ni]);
            }
        }
    }
}

// ---------------- Fused mid levels 11..8 at S=32. 256 blocks, 512 threads, breg[16][2].
__global__ __attribute__((amdgpu_waves_per_eu(2, 2))) __launch_bounds__(512)
void k_mid(const unsigned short* __restrict__ prev,
           unsigned short* __restrict__ outbuf,
           const int* __restrict__ op_ids,
           const unsigned short* __restrict__ T0,
           const float* __restrict__ carr,
           const float* __restrict__ gamma,
           const float* __restrict__ beta,
           const unsigned short* __restrict__ WTbf) {
    __shared__ unsigned short sA[64 * 256];
    __shared__ unsigned short sB[64 * 256];
    __shared__ float s_part[8][64][2];
    int b = blockIdx.x >> 5;
    int q = blockIdx.x & 31;
    int t = threadIdx.x;
    int wid = t >> 6, lane = t & 63;
    int l15 = lane & 15, l4 = lane >> 4;

    bf16x8 breg[16][2];
#pragma unroll
    for (int kk = 0; kk < 16; kk++) {
        int k0 = kk * 32 + l4 * 8;
        int hi = k0 >> 8;
        int innerk = k0 & 255;
        const unsigned short* Wb = WTbf + (long)(256 + hi * 256) * 256;
#pragma unroll
        for (int ni = 0; ni < 2; ni++) {
            int cn = wid * 32 + ni * 16 + l15;
            breg[kk][ni] = *(const bf16x8*)(Wb + (long)cn * 256 + innerk);
        }
    }

    float gv[2], bv[2];
#pragma unroll
    for (int ni = 0; ni < 2; ni++) {
        int c = wid * 32 + ni * 16 + l15;
        gv[ni] = gamma[c];
        bv[ni] = beta[c];
    }

    unsigned short* cur = sA;
    unsigned short* nxt = sB;

    for (int ld = 11; ld >= 8; ld--) {
        int ng = 1 << ld;
        int m = ng >> 5;            // 64, 32, 16, 8
        int mtiles = (m + 15) >> 4; // 4, 2, 1, 1

        float tv[4][4][2];
#pragma unroll
        for (int mi = 0; mi < 4; mi++)
            if (mi < mtiles)
#pragma unroll
                for (int r = 0; r < 4; r++) {
                    int row = mi * 16 + l4 * 4 + r;
                    int rc = row < m ? row : m - 1;
                    int nid = op_ids[b * 16383 + (ng - 1) + q * m + rc];
#pragma unroll
                    for (int ni = 0; ni < 2; ni++)
                        tv[mi][r][ni] = bf2f(T0[(long)nid * 256 + wid * 32 + ni * 16 + l15]);
                }

        f32x4 acc[4][2] = {};
        if (ld == 11) {
            const unsigned short* X = prev + ((long)b * 4096 + q * 128) * 256;
#pragma unroll
            for (int kk = 0; kk < 16; kk++) {
                int k0 = kk * 32 + l4 * 8;
                bf16x8 af[4];
#pragma unroll
                for (int mi = 0; mi < 4; mi++)
                    af[mi] = *(const bf16x8*)(X + (long)(mi * 16 + l15) * 512 + k0);
#pragma unroll
                for (int mi = 0; mi < 4; mi++)
#pragma unroll
                    for (int ni = 0; ni < 2; ni++)
                        acc[mi][ni] = __builtin_amdgcn_mfma_f32_16x16x32_bf16(af[mi], breg[kk][ni],
                                                                             acc[mi][ni], 0, 0, 0);
            }
        } else {
#pragma unroll
            for (int kk = 0; kk < 16; kk++) {
                int k0 = kk * 32 + l4 * 8;
                int hi = k0 >> 8;
                int binr = (k0 & 255) * 2;
                bf16x8 af[4];
#pragma unroll
                for (int mi = 0; mi < 4; mi++)
                    if (mi < mtiles) {
                        int node = 2 * (mi * 16 + l15) + hi;
                        af[mi] = *(const bf16x8*)((const char*)cur + node * 512 +
                                                  (binr ^ (((node >> 1) & 7) << 4)));
                    }
#pragma unroll
                for (int mi = 0; mi < 4; mi++)
                    if (mi < mtiles)
#pragma unroll
                        for (int ni = 0; ni < 2; ni++)
                            acc[mi][ni] = __builtin_amdgcn_mfma_f32_16x16x32_bf16(
                                af[mi], breg[kk][ni], acc[mi][ni], 0, 0, 0);
            }
        }

        const float* carr_d = carr + ld * 256;
        float cv[2];
#pragma unroll
        for (int ni = 0; ni < 2; ni++) cv[ni] = carr_d[wid * 32 + ni * 16 + l15];

#pragma unroll
        for (int mi = 0; mi < 4; mi++)
            if (mi < mtiles)
#pragma unroll
                for (int r = 0; r < 4; r++) {
                    float s = 0.f, s2 = 0.f;
#pragma unroll
                    for (int ni = 0; ni < 2; ni++) {
                        float hh = fmaxf(acc[mi][ni][r] + tv[mi][r][ni] + cv[ni], 0.f);
                        acc[mi][ni][r] = hh;
                        s += hh;
                        s2 += hh * hh;
                    }
#pragma unroll
                    for (int m2 = 1; m2 < 16; m2 <<= 1) {
                        s += __shfl_xor(s, m2);
                        s2 += __shfl_xor(s2, m2);
                    }
                    if (l15 == 0) {
                        int row = mi * 16 + l4 * 4 + r;
                        s_part[wid][row][0] = s;
                        s_part[wid][row][1] = s2;
                    }
                }
        __syncthreads();

#pragma unroll
        for (int mi = 0; mi < 4; mi++)
            if (mi < mtiles)
#pragma unroll
                for (int r = 0; r < 4; r++) {
                    int row = mi * 16 + l4 * 4 + r;
                    if (row < m) {
                        float s = 0.f, s2 = 0.f;
#pragma unroll
                        for (int w = 0; w < 8; w++) {
                            s += s_part[w][row][0];
                            s2 += s_part[w][row][1];
                        }
                        float mu = s * (1.f / 256.f);
                        float rs = rsqrtf(s2 * (1.f / 256.f) - mu * mu + 1e-5f);
#pragma unroll
                        for (int ni = 0; ni < 2; ni++) {
                            int c = wid * 32 + ni * 16 + l15;
                            float val = (acc[mi][ni][r] - mu) * rs * gv[ni] + bv[ni];
                            if (ld == 8) {
                                outbuf[((long)b * 256 + q * 8 + row) * 256 + c] = f2bf(val);
                            } else {
                                *(unsigned short*)((char*)nxt + row * 512 +
                                                   ((c * 2) ^ (((row >> 1) & 7) << 4))) = f2bf(val);
                            }
                        }
                    }
                }
        __syncthreads();
        unsigned short* tmp = cur;
        cur = nxt;
        nxt = tmp;
    }
}

// ---------------- Subtree tail: levels 7..3 at S=8. 64 blocks, 512 threads, breg[16][2].
__global__ __attribute__((amdgpu_waves_per_eu(2, 2))) __launch_bounds__(512)
void k_tail(const unsigned short* __restrict__ prev,
            const int* __restrict__ op_ids,
            const unsigned short* __restrict__ T0,
            const float* __restrict__ carr,
            const float* __restrict__ gamma,
            const float* __restrict__ beta,
            const unsigned short* __restrict__ WTbf,
            unsigned short* __restrict__ mid) {
    __shared__ unsigned short sA[32 * 256];
    __shared__ unsigned short sB[32 * 256];
    __shared__ int s_nid_all[255];
    __shared__ float s_part[8][16][2];
    int b = blockIdx.x >> 3;
    int q = blockIdx.x & 7;
    int t = threadIdx.x;
    int wid = t >> 6, lane = t & 63;
    int l15 = lane & 15, l4 = lane >> 4;

    bf16x8 breg[16][2];
#pragma unroll
    for (int kk = 0; kk < 16; kk++) {
        int k0 = kk * 32 + l4 * 8;
        int hi = k0 >> 8;
        int innerk = k0 & 255;
        const unsigned short* Wb = WTbf + (long)(256 + hi * 256) * 256;
#pragma unroll
        for (int ni = 0; ni < 2; ni++) {
            int cn = wid * 32 + ni * 16 + l15;
            breg[kk][ni] = *(const bf16x8*)(Wb + (long)cn * 256 + innerk);
        }
    }

    if (t < 255) s_nid_all[t] = op_ids[b * 16383 + t];
    float gv[2], bv[2];
#pragma unroll
    for (int ni = 0; ni < 2; ni++) {
        int c = wid * 32 + ni * 16 + l15;
        gv[ni] = gamma[c];
        bv[ni] = beta[c];
    }
    __syncthreads();

    unsigned short* cur = sA;
    unsigned short* nxt = sB;

    for (int ld = 7; ld >= 3; ld--) {
        int ng = 1 << ld;
        int m = ng >> 3;

        float tv[4][2];
#pragma unroll
        for (int r = 0; r < 4; r++) {
            int row = l4 * 4 + r;
            int rc = row < m ? row : m - 1;
            int nid = s_nid_all[(ng - 1) + q * m + rc];
#pragma unroll
            for (int ni = 0; ni < 2; ni++)
                tv[r][ni] = bf2f(T0[(long)nid * 256 + wid * 32 + ni * 16 + l15]);
        }

        f32x4 acc[2] = {};
        if (ld == 7) {
            const unsigned short* X = prev + ((long)b * 256 + q * 32) * 256;
#pragma unroll
            for (int kk = 0; kk < 16; kk++) {
                int k0 = kk * 32 + l4 * 8;
                bf16x8 af = *(const bf16x8*)(X + (long)l15 * 512 + k0);
#pragma unroll
                for (int ni = 0; ni < 2; ni++)
                    acc[ni] = __builtin_amdgcn_mfma_f32_16x16x32_bf16(af, breg[kk][ni], acc[ni],
                                                                      0, 0, 0);
            }
        } else {
#pragma unroll
            for (int kk = 0; kk < 16; kk++) {
                int k0 = kk * 32 + l4 * 8;
                int hi = k0 >> 8;
                int binr = (k0 & 255) * 2;
                int node = 2 * l15 + hi;
                bf16x8 af = *(const bf16x8*)((const char*)cur + node * 512 +
                                             (binr ^ (((node >> 1) & 7) << 4)));
#pragma unroll
                for (int ni = 0; ni < 2; ni++)
                    acc[ni] = __builtin_amdgcn_mfma_f32_16x16x32_bf16(af, breg[kk][ni], acc[ni],
                                                                      0, 0, 0);
            }
        }

        const float* carr_d = carr + ld * 256;
        float cv[2];
#pragma unroll
        for (int ni = 0; ni < 2; ni++) cv[ni] = carr_d[wid * 32 + ni * 16 + l15];

#pragma unroll
        for (int r = 0; r < 4; r++) {
            float s = 0.f, s2 = 0.f;
#pragma unroll
            for (int ni = 0; ni < 2; ni++) {
                float hh = fmaxf(acc[ni][r] + tv[r][ni] + cv[ni], 0.f);
                acc[ni][r] = hh;
                s += hh;
                s2 += hh * hh;
            }
#pragma unroll
            for (int m2 = 1; m2 < 16; m2 <<= 1) {
                s += __shfl_xor(s, m2);
                s2 += __shfl_xor(s2, m2);
            }
            if (l15 == 0) {
                int row = l4 * 4 + r;
                s_part[wid][row][0] = s;
                s_part[wid][row][1] = s2;
            }
        }
        __syncthreads();

#pragma unroll
        for (int r = 0; r < 4; r++) {
            int row = l4 * 4 + r;
            if (row < m) {
                float s = 0.f, s2 = 0.f;
#pragma unroll
                for (int w = 0; w < 8; w++) {
                    s += s_part[w][row][0];
                    s2 += s_part[w][row][1];
                }
                float mu = s * (1.f / 256.f);
                float rs = rsqrtf(s2 * (1.f / 256.f) - mu * mu + 1e-5f);
#pragma unroll
                for (int ni = 0; ni < 2; ni++) {
                    int c = wid * 32 + ni * 16 + l15;
                    float val = (acc[ni][r] - mu) * rs * gv[ni] + bv[ni];
                    if (ld == 3) {
                        mid[(long)(b * 8 + q) * 256 + c] = f2bf(val);
                    } else {
                        *(unsigned short*)((char*)nxt + row * 512 +
                                           ((c * 2) ^ (((row >> 1) & 7) << 4))) = f2bf(val);
                    }
                }
            }
        }
        __syncthreads();
        unsigned short* tmp = cur;
        cur = nxt;
        nxt = tmp;
    }
}

// ---------------- Root: levels 2..0 in one block (256 threads, 4 waves x 64 cols).
__global__ __launch_bounds__(256) void k_root2(const unsigned short* __restrict__ mid,
                                               const int* __restrict__ op_ids,
                                               const unsigned short* __restrict__ T0,
                                               const float* __restrict__ carr,
                                               const float* __restrict__ gamma,
                                               const float* __restrict__ beta,
                                               const unsigned short* __restrict__ WTbf,
                                               float* __restrict__ out) {
    __shared__ unsigned short sL2[32 * 256];
    __shared__ unsigned short sL1[16 * 256];
    __shared__ float s_part[4][32][2];
    __shared__ int s_n2[32], s_n1[16], s_n0[8];
    int t = threadIdx.x;
    int wid = t >> 6, lane = t & 63;
    int l15 = lane & 15, l4 = lane >> 4;

    if (t < 32) s_n2[t] = op_ids[(t >> 2) * 16383 + 3 + (t & 3)];
    if (t < 16) s_n1[t] = op_ids[(t >> 1) * 16383 + 1 + (t & 1)];
    if (t < 8) s_n0[t] = op_ids[t * 16383];
    float gv[4], bv[4];
#pragma unroll
    for (int ni = 0; ni < 4; ni++) {
        int c = wid * 64 + ni * 16 + l15;
        gv[ni] = gamma[c];
        bv[ni] = beta[c];
    }
    __syncthreads();

    // ---- Level 2: 32 rows, A from mid
    {
        f32x4 acc[2][4] = {};
        for (int kk = 0; kk < 16; kk++) {
            int k0 = kk * 32 + l4 * 8;
            int hi = k0 >> 8;
            int innerk = k0 & 255;
            bf16x8 af[2], bfr[4];
#pragma unroll
            for (int mi = 0; mi < 2; mi++)
                af[mi] = *(const bf16x8*)(mid + (long)(mi * 16 + l15) * 512 + k0);
            const unsigned short* Wb = WTbf + (long)(256 + hi * 256) * 256;
#pragma unroll
            for (int ni = 0; ni < 4; ni++) {
                int cn = wid * 64 + ni * 16 + l15;
                bfr[ni] = *(const bf16x8*)(Wb + (long)cn * 256 + innerk);
            }
#pragma unroll
            for (int mi = 0; mi < 2; mi++)
#pragma unroll
                for (int ni = 0; ni < 4; ni++)
                    acc[mi][ni] = __builtin_amdgcn_mfma_f32_16x16x32_bf16(af[mi], bfr[ni],
                                                                         acc[mi][ni], 0, 0, 0);
        }
        const float* carr2 = carr + 2 * 256;
        float cv[4];
#pragma unroll
        for (int ni = 0; ni < 4; ni++) cv[ni] = carr2[wid * 64 + ni * 16 + l15];
#pragma unroll
        for (int mi = 0; mi < 2; mi++)
#pragma unroll
            for (int r = 0; r < 4; r++) {
                int row = mi * 16 + l4 * 4 + r;
                int nid = s_n2[row];
                float s = 0.f, s2 = 0.f;
#pragma unroll
                for (int ni = 0; ni < 4; ni++) {
                    int c = wid * 64 + ni * 16 + l15;
                    float h = fmaxf(acc[mi][ni][r] + bf2f(T0[(long)nid * 256 + c]) + cv[ni], 0.f);
                    acc[mi][ni][r] = h;
                    s += h;
                    s2 += h * h;
                }
#pragma unroll
                for (int m = 1; m < 16; m <<= 1) {
                    s += __shfl_xor(s, m);
                    s2 += __shfl_xor(s2, m);
                }
                if (l15 == 0) {
                    s_part[wid][row][0] = s;
                    s_part[wid][row][1] = s2;
                }
            }
        __syncthreads();
#pragma unroll
        for (int mi = 0; mi < 2; mi++)
#pragma unroll
            for (int r = 0; r < 4; r++) {
                int row = mi * 16 + l4 * 4 + r;
                float s = s_part[0][row][0] + s_part[1][row][0] + s_part[2][row][0] + s_part[3][row][0];
                float s2 = s_part[0][row][1] + s_part[1][row][1] + s_part[2][row][1] + s_part[3][row][1];
                float mu = s * (1.f / 256.f);
                float rs = rsqrtf(s2 * (1.f / 256.f) - mu * mu + 1e-5f);
#pragma unroll
                for (int ni = 0; ni < 4; ni++) {
                    int c = wid * 64 + ni * 16 + l15;
                    *(unsigned short*)((char*)sL2 + row * 512 +
                                       ((c * 2) ^ (((row >> 1) & 7) << 4))) =
                        f2bf((acc[mi][ni][r] - mu) * rs * gv[ni] + bv[ni]);
                }
            }
        __syncthreads();
    }

    // ---- Level 1: 16 rows
    {
        f32x4 acc[4] = {};
        for (int kk = 0; kk < 16; kk++) {
            int k0 = kk * 32 + l4 * 8;
            int hi = k0 >> 8;
            int innerk = k0 & 255;
            int binr = (k0 & 255) * 2;
            int node = 2 * l15 + hi;
            bf16x8 af = *(const bf16x8*)((const char*)sL2 + node * 512 +
                                         (binr ^ (((node >> 1) & 7) << 4)));
            const unsigned short* Wb = WTbf + (long)(256 + hi * 256) * 256;
#pragma unroll
            for (int ni = 0; ni < 4; ni++) {
                int cn = wid * 64 + ni * 16 + l15;
                bf16x8 bfr = *(const bf16x8*)(Wb + (long)cn * 256 + innerk);
                acc[ni] = __builtin_amdgcn_mfma_f32_16x16x32_bf16(af, bfr, acc[ni], 0, 0, 0);
            }
        }
        const float* carr1 = carr + 256;
        float cv[4];
#pragma unroll
        for (int ni = 0; ni < 4; ni++) cv[ni] = carr1[wid * 64 + ni * 16 + l15];
#pragma unroll
        for (int r = 0; r < 4; r++) {
            int row = l4 * 4 + r;
            int nid = s_n1[row];
            float s = 0.f, s2 = 0.f;
#pragma unroll
            for (int ni = 0; ni < 4; ni++) {
                int c = wid * 64 + ni * 16 + l15;
                float h = fmaxf(acc[ni][r] + bf2f(T0[(long)nid * 256 + c]) + cv[ni], 0.f);
                acc[ni][r] = h;
                s += h;
                s2 += h * h;
            }
#pragma unroll
            for (int m = 1; m < 16; m <<= 1) {
                s += __shfl_xor(s, m);
                s2 += __shfl_xor(s2, m);
            }
            if (l15 == 0) {
                s_part[wid][row][0] = s;
                s_part[wid][row][1] = s2;
            }
        }
        __syncthreads();
#pragma unroll
        for (int r = 0; r < 4; r++) {
            int row = l4 * 4 + r;
            float s = s_part[0][row][0] + s_part[1][row][0] + s_part[2][row][0] + s_part[3][row][0];
            float s2 = s_part[0][row][1] + s_part[1][row][1] + s_part[2][row][1] + s_part[3][row][1];
            float mu = s * (1.f / 256.f);
            float rs = rsqrtf(s2 * (1.f / 256.f) - mu * mu + 1e-5f);
#pragma unroll
            for (int ni = 0; ni < 4; ni++) {
                int c = wid * 64 + ni * 16 + l15;
                *(unsigned short*)((char*)sL1 + row * 512 +
                                   ((c * 2) ^ (((row >> 1) & 7) << 4))) =
                    f2bf((acc[ni][r] - mu) * rs * gv[ni] + bv[ni]);
            }
        }
        __syncthreads();
    }

    // ---- Level 0: 8 rows -> out
    {
        f32x4 acc[4] = {};
        for (int kk = 0; kk < 16; kk++) {
            int k0 = kk * 32 + l4 * 8;
            int hi = k0 >> 8;
            int innerk = k0 & 255;
            int binr = (k0 & 255) * 2;
            int node = 2 * (l15 & 7) + hi;
            bf16x8 af = *(const bf16x8*)((const char*)sL1 + node * 512 +
                                         (binr ^ (((node >> 1) & 7) << 4)));
            const unsigned short* Wb = WTbf + (long)(256 + hi * 256) * 256;
#pragma unroll
            for (int ni = 0; ni < 4; ni++) {
                int cn = wid * 64 + ni * 16 + l15;
                bf16x8 bfr = *(const bf16x8*)(Wb + (long)cn * 256 + innerk);
                acc[ni] = __builtin_amdgcn_mfma_f32_16x16x32_bf16(af, bfr, acc[ni], 0, 0, 0);
            }
        }
        float cv[4];
#pragma unroll
        for (int ni = 0; ni < 4; ni++) cv[ni] = carr[wid * 64 + ni * 16 + l15];
#pragma unroll
        for (int r = 0; r < 4; r++) {
            int row = l4 * 4 + r;
            int nid = s_n0[row & 7];
            float s = 0.f, s2 = 0.f;
#pragma unroll
            for (int ni = 0; ni < 4; ni++) {
                int c = wid * 64 + ni * 16 + l15;
                float h = fmaxf(acc[ni][r] + bf2f(T0[(long)nid * 256 + c]) + cv[ni], 0.f);
                acc[ni][r] = h;
                s += h;
                s2 += h * h;
            }
#pragma unroll
            for (int m = 1; m < 16; m <<= 1) {
                s += __shfl_xor(s, m);
                s2 += __shfl_xor(s2, m);
            }
            if (l15 == 0) {
                s_part[wid][row][0] = s;
                s_part[wid][row][1] = s2;
            }
        }
        __syncthreads();
#pragma unroll
        for (int r = 0; r < 4; r++) {
            int row = l4 * 4 + r;
            if (row < 8) {
                float s = s_part[0][row][0] + s_part[1][row][0] + s_part[2][row][0] + s_part[3][row][0];
                float s2 = s_part[0][row][1] + s_part[1][row][1] + s_part[2][row][1] + s_part[3][row][1];
                float mu = s * (1.f / 256.f);
                float rs = rsqrtf(s2 * (1.f / 256.f) - mu * mu + 1e-5f);
#pragma unroll
                for (int ni = 0; ni < 4; ni++) {
                    int c = wid * 64 + ni * 16 + l15;
                    out[row * 256 + c] = (acc[ni][r] - mu) * rs * gv[ni] + bv[ni];
                }
            }
        }
    }
}

extern "C" void kernel_launch(void* const* d_in, const int* in_sizes, int n_in,
                              void* d_out, int out_size, void* d_ws, size_t ws_size,
                              hipStream_t stream) {
    const int* leaf_ids = (const int*)d_in[0];
    const int* op_ids = (const int*)d_in[1];
    const float* tok = (const float*)d_in[2];
    const float* dep = (const float*)d_in[3];
    const float* idx = (const float*)d_in[4];
    const float* W = (const float*)d_in[5];
    const float* bvec = (const float*)d_in[6];
    const float* gamma = (const float*)d_in[7];
    const float* beta = (const float*)d_in[8];
    float* out = (float*)d_out;

    char* ws = (char*)d_ws;
    unsigned short* T = (unsigned short*)(ws);                            // 1.5 MB (bf16 T0|T1|T2)
    unsigned short* WTbf = (unsigned short*)(ws + 3u * 1024 * 1024);     // 384 KB
    unsigned short* tokbf = (unsigned short*)(ws + 3u * 1024 * 1024 + 512 * 1024);  // 512 KB
    float* carr = (float*)(ws + 4u * 1024 * 1024 + 64 * 1024);           // 14 KB
    float* carrp = (float*)(ws + 5u * 1024 * 1024);                      // 112 KB partials
    unsigned short* mid = (unsigned short*)(ws + 6u * 1024 * 1024);      // 32 KB (64x256 bf16)
    unsigned short* ebufA = (unsigned short*)(ws + 8u * 1024 * 1024);    // 16 MB (level-12 out)
    unsigned short* ebufB = (unsigned short*)(ws + 40u * 1024 * 1024);   // 1 MB (level-8 out)

    k_prep<<<416, 256, 0, stream>>>(tok, W, dep, idx, bvec, tokbf, WTbf, carrp);
    k_carrsum<<<14, 256, 0, stream>>>(carrp, carr);
    k_ttmm<<<dim3(32, 3), 256, 0, stream>>>(tokbf, WTbf, T);

    // levels 13+12 -> ebufA (4096 rows/batch), 32 rows/block
    k_level12f<<<dim3(128, 8), 256, 0, stream>>>(leaf_ids, op_ids, T, carr, gamma, beta, WTbf,
                                                 ebufA);
    // levels 11..8 (256 blocks: batch x 1/32 subtree) -> ebufB (level-8 out, 256 rows/batch)
    k_mid<<<256, 512, 0, stream>>>(ebufA, ebufB, op_ids, T, carr, gamma, beta, WTbf);
    // levels 7..3 (64 blocks: batch x eighth) -> mid (level-3 out, 8x256 per batch)
    k_tail<<<64, 512, 0, stream>>>(ebufB, op_ids, T, carr, gamma, beta, WTbf, mid);
    // levels 2..0
    k_root2<<<1, 256, 0, stream>>>(mid, op_ids, T, carr, gamma, beta, WTbf, out);
}

// Round 21
// 181.349 us; speedup vs baseline: 1.1264x; 1.0148x over previous
//
#include <hip/hip_runtime.h>

typedef float f32x4 __attribute__((ext_vector_type(4)));
typedef short bf16x8 __attribute__((ext_vector_type(8)));

__device__ inline unsigned short f2bf(float f) {
    unsigned int u = __builtin_bit_cast(unsigned int, f);
    unsigned int r = (u + 0x7FFFu + ((u >> 16) & 1u)) >> 16;
    return (unsigned short)r;
}
__device__ inline float bf2f(unsigned short u) {
    unsigned int x = ((unsigned int)u) << 16;
    return __builtin_bit_cast(float, x);
}
__device__ inline float f4get(const float4& v, int e) {
    return e == 0 ? v.x : (e == 1 ? v.y : (e == 2 ? v.z : v.w));
}

// ---------------- Combined prep: tok->bf16 | W transpose->bf16 | carr split-K partials
__global__ __launch_bounds__(256) void k_prep(const float* __restrict__ tok,
                                              const float* __restrict__ W,
                                              const float* __restrict__ dep,
                                              const float* __restrict__ idx,
                                              const float* __restrict__ bvec,
                                              unsigned short* __restrict__ tokbf,
                                              unsigned short* __restrict__ WTbf,
                                              float* __restrict__ carrp) {
    __shared__ float s_tile[64][65];
    int bx = blockIdx.x;
    if (bx < 256) {
        int i = bx * 256 + threadIdx.x;
        const float4 v = *(const float4*)(tok + (long)i * 4);
        ushort4 o;
        o.x = f2bf(v.x); o.y = f2bf(v.y); o.z = f2bf(v.z); o.w = f2bf(v.w);
        *(ushort4*)(tokbf + (long)i * 4) = o;
    } else if (bx < 304) {
        int bb = bx - 256;
        int sec = bb >> 4;
        int tt = bb & 15;
        int k0 = (tt >> 2) * 64, j0 = (tt & 3) * 64;
        int tx = threadIdx.x & 63, ty = threadIdx.x >> 6;
#pragma unroll
        for (int r = 0; r < 16; r++) {
            int kk = ty * 16 + r;
            s_tile[kk][tx] = W[(sec * 256 + k0 + kk) * 256 + j0 + tx];
        }
        __syncthreads();
#pragma unroll
        for (int r = 0; r < 16; r++) {
            int jj = ty * 16 + r;
            WTbf[(sec * 256 + j0 + jj) * 256 + k0 + tx] = f2bf(s_tile[tx][jj]);
        }
    } else {
        int q = bx - 304;
        int d = q >> 3;
        int c = q & 7;
        int j = threadIdx.x;
        float acc = (c == 0) ? bvec[j] : 0.f;
        int kbeg = c * 32, kend = kbeg + 32;
#pragma unroll 4
        for (int k = kbeg; k < kend; k++) {
            float dv = dep[(d + 1) * 256 + k];
            acc += dv * (W[(768 + k) * 256 + j] + W[(1280 + k) * 256 + j]);
            acc += idx[k] * W[(1024 + k) * 256 + j];
            acc += idx[256 + k] * W[(1536 + k) * 256 + j];
        }
        if (d == 13) {
#pragma unroll 4
            for (int k = kbeg; k < kend; k++) {
                float dv = dep[14 * 256 + k];
                acc += dv * (W[(256 + k) * 256 + j] + W[(512 + k) * 256 + j]);
            }
        }
        carrp[(long)q * 256 + j] = acc;
    }
}

// ---------------- carr reduce
__global__ __launch_bounds__(256) void k_carrsum(const float* __restrict__ carrp,
                                                 float* __restrict__ carr) {
    int d = blockIdx.x;
    int j = threadIdx.x;
    float s = 0.f;
#pragma unroll
    for (int c = 0; c < 8; c++) s += carrp[(long)(d * 8 + c) * 256 + j];
    carr[d * 256 + j] = s;
}

// ---------------- T tables via MFMA (bf16 out)
__global__ __launch_bounds__(256) void k_ttmm(const unsigned short* __restrict__ tokbf,
                                              const unsigned short* __restrict__ WTbf,
                                              unsigned short* __restrict__ T) {
    int wid = threadIdx.x >> 6, lane = threadIdx.x & 63;
    int l15 = lane & 15, l4 = lane >> 4;
    int row0 = blockIdx.x * 32;
    int sec = blockIdx.y;

    f32x4 acc[2][4] = {};
    for (int kk = 0; kk < 8; kk++) {
        int k0 = kk * 32 + l4 * 8;
        bf16x8 af[2], bfr[4];
#pragma unroll
        for (int mi = 0; mi < 2; mi++)
            af[mi] = *(const bf16x8*)(tokbf + (long)(row0 + mi * 16 + l15) * 256 + k0);
#pragma unroll
        for (int ni = 0; ni < 4; ni++)
            bfr[ni] = *(const bf16x8*)(WTbf + (long)(sec * 256 + wid * 64 + ni * 16 + l15) * 256 + k0);
#pragma unroll
        for (int mi = 0; mi < 2; mi++)
#pragma unroll
            for (int ni = 0; ni < 4; ni++)
                acc[mi][ni] = __builtin_amdgcn_mfma_f32_16x16x32_bf16(af[mi], bfr[ni],
                                                                     acc[mi][ni], 0, 0, 0);
    }
#pragma unroll
    for (int mi = 0; mi < 2; mi++)
#pragma unroll
        for (int r = 0; r < 4; r++) {
            int row = row0 + mi * 16 + l4 * 4 + r;
#pragma unroll
            for (int ni = 0; ni < 4; ni++) {
                int c = wid * 64 + ni * 16 + l15;
                T[(long)sec * 262144 + (long)row * 256 + c] = f2bf(acc[mi][ni][r]);
            }
        }
}

// ---------------- Fused level 13+12: gather = node-per-16-lanes, 16B table loads.
// Epilogue T0 values prefetched into registers BEFORE the GEMM (latency hidden under MFMA).
__global__ __launch_bounds__(256) void k_level12f(const int* __restrict__ leaf_ids,
                                                  const int* __restrict__ op_ids,
                                                  const unsigned short* __restrict__ T,
                                                  const float* __restrict__ carr,
                                                  const float* __restrict__ gamma,
                                                  const float* __restrict__ beta,
                                                  const unsigned short* __restrict__ WTbf,
                                                  unsigned short* __restrict__ ebuf_out) {
    __shared__ unsigned short sA[64 * 256];
    __shared__ int s_nid13[64];
    __shared__ int s_leaf[128];
    __shared__ int s_nid[32];
    __shared__ float s_part[4][32][2];
    int b = blockIdx.y;
    int row0 = blockIdx.x * 32;
    int t = threadIdx.x;
    int wid = t >> 6, lane = t & 63;
    int l15 = lane & 15, l4 = lane >> 4;
    const unsigned short* T0 = T;
    const unsigned short* T1 = T + 262144;
    const unsigned short* T2 = T + 524288;

    if (t < 64) s_nid13[t] = op_ids[b * 16383 + 8191 + 2 * row0 + t];
    if (t < 128) s_leaf[t] = leaf_ids[b * 16384 + 4 * row0 + t];
    if (t < 32) s_nid[t] = op_ids[b * 16383 + 4095 + row0 + t];
    __syncthreads();

    {
        const float* c13 = carr + 13 * 256;
        float4 dd[4], g4[4], b4[4];
#pragma unroll
        for (int q = 0; q < 4; q++) {
            int c0 = l15 * 16 + q * 4;
            dd[q] = *(const float4*)(c13 + c0);
            g4[q] = *(const float4*)(gamma + c0);
            b4[q] = *(const float4*)(beta + c0);
        }
#pragma unroll
        for (int j = 0; j < 4; j++) {
            int node = wid * 16 + j * 4 + l4;
            int nid = s_nid13[node];
            int ll = s_leaf[2 * node], lr = s_leaf[2 * node + 1];
            bf16x8 a0 = *(const bf16x8*)(T0 + (long)nid * 256 + l15 * 16);
            bf16x8 a1 = *(const bf16x8*)(T0 + (long)nid * 256 + l15 * 16 + 8);
            bf16x8 b0 = *(const bf16x8*)(T1 + (long)ll * 256 + l15 * 16);
            bf16x8 b1 = *(const bf16x8*)(T1 + (long)ll * 256 + l15 * 16 + 8);
            bf16x8 c0 = *(const bf16x8*)(T2 + (long)lr * 256 + l15 * 16);
            bf16x8 c1 = *(const bf16x8*)(T2 + (long)lr * 256 + l15 * 16 + 8);
            float v[16];
            float s = 0.f, s2 = 0.f;
#pragma unroll
            for (int e = 0; e < 8; e++) {
                float x = bf2f((unsigned short)a0[e]) + bf2f((unsigned short)b0[e]) +
                          bf2f((unsigned short)c0[e]) + f4get(dd[e >> 2], e & 3);
                x = fmaxf(x, 0.f);
                v[e] = x;
                s += x;
                s2 += x * x;
            }
#pragma unroll
            for (int e = 0; e < 8; e++) {
                float x = bf2f((unsigned short)a1[e]) + bf2f((unsigned short)b1[e]) +
                          bf2f((unsigned short)c1[e]) + f4get(dd[2 + (e >> 2)], e & 3);
                x = fmaxf(x, 0.f);
                v[8 + e] = x;
                s += x;
                s2 += x * x;
            }
#pragma unroll
            for (int m = 1; m < 16; m <<= 1) {
                s += __shfl_xor(s, m);
                s2 += __shfl_xor(s2, m);
            }
            float mu = s * (1.f / 256.f);
            float rs = rsqrtf(s2 * (1.f / 256.f) - mu * mu + 1e-5f);
            int swz = ((node >> 1) & 7) << 4;
            bf16x8 o0, o1;
#pragma unroll
            for (int e = 0; e < 8; e++) {
                o0[e] = (short)f2bf((v[e] - mu) * rs * f4get(g4[e >> 2], e & 3) +
                                    f4get(b4[e >> 2], e & 3));
                o1[e] = (short)f2bf((v[8 + e] - mu) * rs * f4get(g4[2 + (e >> 2)], e & 3) +
                                    f4get(b4[2 + (e >> 2)], e & 3));
            }
            *(bf16x8*)((char*)sA + node * 512 + ((l15 * 32) ^ swz)) = o0;
            *(bf16x8*)((char*)sA + node * 512 + ((l15 * 32 + 16) ^ swz)) = o1;
        }
    }
    __syncthreads();

    // Prefetch epilogue T0 values (depend only on s_nid) — latency hides under the GEMM
    float tvx[2][4][4];
#pragma unroll
    for (int mi = 0; mi < 2; mi++)
#pragma unroll
        for (int r = 0; r < 4; r++) {
            int row = mi * 16 + l4 * 4 + r;
            int nid = s_nid[row];
#pragma unroll
            for (int ni = 0; ni < 4; ni++)
                tvx[mi][r][ni] = bf2f(T0[(long)nid * 256 + wid * 64 + ni * 16 + l15]);
        }

    f32x4 acc[2][4] = {};
    for (int kk = 0; kk < 16; kk++) {
        int k0 = kk * 32 + l4 * 8;
        int hi = k0 >> 8;
        int binr = (k0 & 255) * 2;
        bf16x8 af[2], bfr[4];
#pragma unroll
        for (int mi = 0; mi < 2; mi++) {
            int node = 2 * (mi * 16 + l15) + hi;
            af[mi] = *(const bf16x8*)((const char*)sA + node * 512 + (binr ^ (((node >> 1) & 7) << 4)));
        }
        const unsigned short* Wb = WTbf + (long)(256 + hi * 256) * 256;
        int innerk = k0 & 255;
#pragma unroll
        for (int ni = 0; ni < 4; ni++) {
            int cn = wid * 64 + ni * 16 + l15;
            bfr[ni] = *(const bf16x8*)(Wb + (long)cn * 256 + innerk);
        }
#pragma unroll
        for (int mi = 0; mi < 2; mi++)
#pragma unroll
            for (int ni = 0; ni < 4; ni++)
                acc[mi][ni] = __builtin_amdgcn_mfma_f32_16x16x32_bf16(af[mi], bfr[ni],
                                                                     acc[mi][ni], 0, 0, 0);
    }

    const float* carr_d = carr + 12 * 256;
    float cv[4], gv[4], bv[4];
#pragma unroll
    for (int ni = 0; ni < 4; ni++) {
        int c = wid * 64 + ni * 16 + l15;
        cv[ni] = carr_d[c];
        gv[ni] = gamma[c];
        bv[ni] = beta[c];
    }

#pragma unroll
    for (int mi = 0; mi < 2; mi++) {
#pragma unroll
        for (int r = 0; r < 4; r++) {
            int row = mi * 16 + l4 * 4 + r;
            float s = 0.f, s2 = 0.f;
#pragma unroll
            for (int ni = 0; ni < 4; ni++) {
                float h = acc[mi][ni][r] + tvx[mi][r][ni] + cv[ni];
                h = fmaxf(h, 0.f);
                acc[mi][ni][r] = h;
                s += h;
                s2 += h * h;
            }
#pragma unroll
            for (int m = 1; m < 16; m <<= 1) {
                s += __shfl_xor(s, m);
                s2 += __shfl_xor(s2, m);
            }
            if (l15 == 0) {
                s_part[wid][row][0] = s;
                s_part[wid][row][1] = s2;
            }
        }
    }
    __syncthreads();

#pragma unroll
    for (int mi = 0; mi < 2; mi++) {
#pragma unroll
        for (int r = 0; r < 4; r++) {
            int row = mi * 16 + l4 * 4 + r;
            float s = s_part[0][row][0] + s_part[1][row][0] + s_part[2][row][0] + s_part[3][row][0];
            float s2 = s_part[0][row][1] + s_part[1][row][1] + s_part[2][row][1] + s_part[3][row][1];
            float mu = s * (1.f / 256.f);
            float rs = rsqrtf(s2 * (1.f / 256.f) - mu * mu + 1e-5f);
            unsigned short* o = ebuf_out + ((long)b * 4096 + row0 + row) * 256;
#pragma unroll
            for (int ni = 0; ni < 4; ni++) {
                int c = wid * 64 + ni * 16 + l15;
                o[c] = f2bf((acc[mi][ni][r] - mu) * rs * gv[ni] + bv[ni]);
            }
        }
    }
}

// ---------------- Fused mid levels 11..8 at S=32. 256 blocks, 512 threads, breg[16][2].
__global__ __attribute__((amdgpu_waves_per_eu(2, 2))) __launch_bounds__(512)
void k_mid(const unsigned short* __restrict__ prev,
           unsigned short* __restrict__ outbuf,
           const int* __restrict__ op_ids,
           const unsigned short* __restrict__ T0,
           const float* __restrict__ carr,
           const float* __restrict__ gamma,
           const float* __restrict__ beta,
           const unsigned short* __restrict__ WTbf) {
    __shared__ unsigned short sA[64 * 256];
    __shared__ unsigned short sB[64 * 256];
    __shared__ float s_part[8][64][2];
    int b = blockIdx.x >> 5;
    int q = blockIdx.x & 31;
    int t = threadIdx.x;
    int wid = t >> 6, lane = t & 63;
    int l15 = lane & 15, l4 = lane >> 4;

    bf16x8 breg[16][2];
#pragma unroll
    for (int kk = 0; kk < 16; kk++) {
        int k0 = kk * 32 + l4 * 8;
        int hi = k0 >> 8;
        int innerk = k0 & 255;
        const unsigned short* Wb = WTbf + (long)(256 + hi * 256) * 256;
#pragma unroll
        for (int ni = 0; ni < 2; ni++) {
            int cn = wid * 32 + ni * 16 + l15;
            breg[kk][ni] = *(const bf16x8*)(Wb + (long)cn * 256 + innerk);
        }
    }

    float gv[2], bv[2];
#pragma unroll
    for (int ni = 0; ni < 2; ni++) {
        int c = wid * 32 + ni * 16 + l15;
        gv[ni] = gamma[c];
        bv[ni] = beta[c];
    }

    unsigned short* cur = sA;
    unsigned short* nxt = sB;

    for (int ld = 11; ld >= 8; ld--) {
        int ng = 1 << ld;
        int m = ng >> 5;            // 64, 32, 16, 8
        int mtiles = (m + 15) >> 4; // 4, 2, 1, 1

        float tv[4][4][2];
#pragma unroll
        for (int mi = 0; mi < 4; mi++)
            if (mi < mtiles)
#pragma unroll
                for (int r = 0; r < 4; r++) {
                    int row = mi * 16 + l4 * 4 + r;
                    int rc = row < m ? row : m - 1;
                    int nid = op_ids[b * 16383 + (ng - 1) + q * m + rc];
#pragma unroll
                    for (int ni = 0; ni < 2; ni++)
                        tv[mi][r][ni] = bf2f(T0[(long)nid * 256 + wid * 32 + ni * 16 + l15]);
                }

        f32x4 acc[4][2] = {};
        if (ld == 11) {
            const unsigned short* X = prev + ((long)b * 4096 + q * 128) * 256;
#pragma unroll
            for (int kk = 0; kk < 16; kk++) {
                int k0 = kk * 32 + l4 * 8;
                bf16x8 af[4];
#pragma unroll
                for (int mi = 0; mi < 4; mi++)
                    af[mi] = *(const bf16x8*)(X + (long)(mi * 16 + l15) * 512 + k0);
#pragma unroll
                for (int mi = 0; mi < 4; mi++)
#pragma unroll
                    for (int ni = 0; ni < 2; ni++)
                        acc[mi][ni] = __builtin_amdgcn_mfma_f32_16x16x32_bf16(af[mi], breg[kk][ni],
                                                                             acc[mi][ni], 0, 0, 0);
            }
        } else {
#pragma unroll
            for (int kk = 0; kk < 16; kk++) {
                int k0 = kk * 32 + l4 * 8;
                int hi = k0 >> 8;
                int binr = (k0 & 255) * 2;
                bf16x8 af[4];
#pragma unroll
                for (int mi = 0; mi < 4; mi++)
                    if (mi < mtiles) {
                        int node = 2 * (mi * 16 + l15) + hi;
                        af[mi] = *(const bf16x8*)((const char*)cur + node * 512 +
                                                  (binr ^ (((node >> 1) & 7) << 4)));
                    }
#pragma unroll
                for (int mi = 0; mi < 4; mi++)
                    if (mi < mtiles)
#pragma unroll
                        for (int ni = 0; ni < 2; ni++)
                            acc[mi][ni] = __builtin_amdgcn_mfma_f32_16x16x32_bf16(
                                af[mi], breg[kk][ni], acc[mi][ni], 0, 0, 0);
            }
        }

        const float* carr_d = carr + ld * 256;
        float cv[2];
#pragma unroll
        for (int ni = 0; ni < 2; ni++) cv[ni] = carr_d[wid * 32 + ni * 16 + l15];

#pragma unroll
        for (int mi = 0; mi < 4; mi++)
            if (mi < mtiles)
#pragma unroll
                for (int r = 0; r < 4; r++) {
                    float s = 0.f, s2 = 0.f;
#pragma unroll
                    for (int ni = 0; ni < 2; ni++) {
                        float hh = fmaxf(acc[mi][ni][r] + tv[mi][r][ni] + cv[ni], 0.f);
                        acc[mi][ni][r] = hh;
                        s += hh;
                        s2 += hh * hh;
                    }
#pragma unroll
                    for (int m2 = 1; m2 < 16; m2 <<= 1) {
                        s += __shfl_xor(s, m2);
                        s2 += __shfl_xor(s2, m2);
                    }
                    if (l15 == 0) {
                        int row = mi * 16 + l4 * 4 + r;
                        s_part[wid][row][0] = s;
                        s_part[wid][row][1] = s2;
                    }
                }
        __syncthreads();

#pragma unroll
        for (int mi = 0; mi < 4; mi++)
            if (mi < mtiles)
#pragma unroll
                for (int r = 0; r < 4; r++) {
                    int row = mi * 16 + l4 * 4 + r;
                    if (row < m) {
                        float s = 0.f, s2 = 0.f;
#pragma unroll
                        for (int w = 0; w < 8; w++) {
                            s += s_part[w][row][0];
                            s2 += s_part[w][row][1];
                        }
                        float mu = s * (1.f / 256.f);
                        float rs = rsqrtf(s2 * (1.f / 256.f) - mu * mu + 1e-5f);
#pragma unroll
                        for (int ni = 0; ni < 2; ni++) {
                            int c = wid * 32 + ni * 16 + l15;
                            float val = (acc[mi][ni][r] - mu) * rs * gv[ni] + bv[ni];
                            if (ld == 8) {
                                outbuf[((long)b * 256 + q * 8 + row) * 256 + c] = f2bf(val);
                            } else {
                                *(unsigned short*)((char*)nxt + row * 512 +
                                                   ((c * 2) ^ (((row >> 1) & 7) << 4))) = f2bf(val);
                            }
                        }
                    }
                }
        __syncthreads();
        unsigned short* tmp = cur;
        cur = nxt;
        nxt = tmp;
    }
}

// ---------------- Subtree tail: levels 7..3 at S=8. 64 blocks, 512 threads, breg[16][2].
__global__ __attribute__((amdgpu_waves_per_eu(2, 2))) __launch_bounds__(512)
void k_tail(const unsigned short* __restrict__ prev,
            const int* __restrict__ op_ids,
            const unsigned short* __restrict__ T0,
            const float* __restrict__ carr,
            const float* __restrict__ gamma,
            const float* __restrict__ beta,
            const unsigned short* __restrict__ WTbf,
            unsigned short* __restrict__ mid) {
    __shared__ unsigned short sA[32 * 256];
    __shared__ unsigned short sB[32 * 256];
    __shared__ int s_nid_all[255];
    __shared__ float s_part[8][16][2];
    int b = blockIdx.x >> 3;
    int q = blockIdx.x & 7;
    int t = threadIdx.x;
    int wid = t >> 6, lane = t & 63;
    int l15 = lane & 15, l4 = lane >> 4;

    bf16x8 breg[16][2];
#pragma unroll
    for (int kk = 0; kk < 16; kk++) {
        int k0 = kk * 32 + l4 * 8;
        int hi = k0 >> 8;
        int innerk = k0 & 255;
        const unsigned short* Wb = WTbf + (long)(256 + hi * 256) * 256;
#pragma unroll
        for (int ni = 0; ni < 2; ni++) {
            int cn = wid * 32 + ni * 16 + l15;
            breg[kk][ni] = *(const bf16x8*)(Wb + (long)cn * 256 + innerk);
        }
    }

    if (t < 255) s_nid_all[t] = op_ids[b * 16383 + t];
    float gv[2], bv[2];
#pragma unroll
    for (int ni = 0; ni < 2; ni++) {
        int c = wid * 32 + ni * 16 + l15;
        gv[ni] = gamma[c];
        bv[ni] = beta[c];
    }
    __syncthreads();

    unsigned short* cur = sA;
    unsigned short* nxt = sB;

    for (int ld = 7; ld >= 3; ld--) {
        int ng = 1 << ld;
        int m = ng >> 3;

        float tv[4][2];
#pragma unroll
        for (int r = 0; r < 4; r++) {
            int row = l4 * 4 + r;
            int rc = row < m ? row : m - 1;
            int nid = s_nid_all[(ng - 1) + q * m + rc];
#pragma unroll
            for (int ni = 0; ni < 2; ni++)
                tv[r][ni] = bf2f(T0[(long)nid * 256 + wid * 32 + ni * 16 + l15]);
        }

        f32x4 acc[2] = {};
        if (ld == 7) {
            const unsigned short* X = prev + ((long)b * 256 + q * 32) * 256;
#pragma unroll
            for (int kk = 0; kk < 16; kk++) {
                int k0 = kk * 32 + l4 * 8;
                bf16x8 af = *(const bf16x8*)(X + (long)l15 * 512 + k0);
#pragma unroll
                for (int ni = 0; ni < 2; ni++)
                    acc[ni] = __builtin_amdgcn_mfma_f32_16x16x32_bf16(af, breg[kk][ni], acc[ni],
                                                                      0, 0, 0);
            }
        } else {
#pragma unroll
            for (int kk = 0; kk < 16; kk++) {
                int k0 = kk * 32 + l4 * 8;
                int hi = k0 >> 8;
                int binr = (k0 & 255) * 2;
                int node = 2 * l15 + hi;
                bf16x8 af = *(const bf16x8*)((const char*)cur + node * 512 +
                                             (binr ^ (((node >> 1) & 7) << 4)));
#pragma unroll
                for (int ni = 0; ni < 2; ni++)
                    acc[ni] = __builtin_amdgcn_mfma_f32_16x16x32_bf16(af, breg[kk][ni], acc[ni],
                                                                      0, 0, 0);
            }
        }

        const float* carr_d = carr + ld * 256;
        float cv[2];
#pragma unroll
        for (int ni = 0; ni < 2; ni++) cv[ni] = carr_d[wid * 32 + ni * 16 + l15];

#pragma unroll
        for (int r = 0; r < 4; r++) {
            float s = 0.f, s2 = 0.f;
#pragma unroll
            for (int ni = 0; ni < 2; ni++) {
                float hh = fmaxf(acc[ni][r] + tv[r][ni] + cv[ni], 0.f);
                acc[ni][r] = hh;
                s += hh;
                s2 += hh * hh;
            }
#pragma unroll
            for (int m2 = 1; m2 < 16; m2 <<= 1) {
                s += __shfl_xor(s, m2);
                s2 += __shfl_xor(s2, m2);
            }
            if (l15 == 0) {
                int row = l4 * 4 + r;
                s_part[wid][row][0] = s;
                s_part[wid][row][1] = s2;
            }
        }
        __syncthreads();

#pragma unroll
        for (int r = 0; r < 4; r++) {
            int row = l4 * 4 + r;
            if (row < m) {
                float s = 0.f, s2 = 0.f;
#pragma unroll
                for (int w = 0; w < 8; w++) {
                    s += s_part[w][row][0];
                    s2 += s_part[w][row][1];
                }
                float mu = s * (1.f / 256.f);
                float rs = rsqrtf(s2 * (1.f / 256.f) - mu * mu + 1e-5f);
#pragma unroll
                for (int ni = 0; ni < 2; ni++) {
                    int c = wid * 32 + ni * 16 + l15;
                    float val = (acc[ni][r] - mu) * rs * gv[ni] + bv[ni];
                    if (ld == 3) {
                        mid[(long)(b * 8 + q) * 256 + c] = f2bf(val);
                    } else {
                        *(unsigned short*)((char*)nxt + row * 512 +
                                           ((c * 2) ^ (((row >> 1) & 7) << 4))) = f2bf(val);
                    }
                }
            }
        }
        __syncthreads();
        unsigned short* tmp = cur;
        cur = nxt;
        nxt = tmp;
    }
}

// ---------------- Root: levels 2..0 in one block (256 threads, 4 waves x 64 cols).
__global__ __launch_bounds__(256) void k_root2(const unsigned short* __restrict__ mid,
                                               const int* __restrict__ op_ids,
                                               const unsigned short* __restrict__ T0,
                                               const float* __restrict__ carr,
                                               const float* __restrict__ gamma,
                                               const float* __restrict__ beta,
                                               const unsigned short* __restrict__ WTbf,
                                               float* __restrict__ out) {
    __shared__ unsigned short sL2[32 * 256];
    __shared__ unsigned short sL1[16 * 256];
    __shared__ float s_part[4][32][2];
    __shared__ int s_n2[32], s_n1[16], s_n0[8];
    int t = threadIdx.x;
    int wid = t >> 6, lane = t & 63;
    int l15 = lane & 15, l4 = lane >> 4;

    if (t < 32) s_n2[t] = op_ids[(t >> 2) * 16383 + 3 + (t & 3)];
    if (t < 16) s_n1[t] = op_ids[(t >> 1) * 16383 + 1 + (t & 1)];
    if (t < 8) s_n0[t] = op_ids[t * 16383];
    float gv[4], bv[4];
#pragma unroll
    for (int ni = 0; ni < 4; ni++) {
        int c = wid * 64 + ni * 16 + l15;
        gv[ni] = gamma[c];
        bv[ni] = beta[c];
    }
    __syncthreads();

    // ---- Level 2: 32 rows, A from mid
    {
        f32x4 acc[2][4] = {};
        for (int kk = 0; kk < 16; kk++) {
            int k0 = kk * 32 + l4 * 8;
            int hi = k0 >> 8;
            int innerk = k0 & 255;
            bf16x8 af[2], bfr[4];
#pragma unroll
            for (int mi = 0; mi < 2; mi++)
                af[mi] = *(const bf16x8*)(mid + (long)(mi * 16 + l15) * 512 + k0);
            const unsigned short* Wb = WTbf + (long)(256 + hi * 256) * 256;
#pragma unroll
            for (int ni = 0; ni < 4; ni++) {
                int cn = wid * 64 + ni * 16 + l15;
                bfr[ni] = *(const bf16x8*)(Wb + (long)cn * 256 + innerk);
            }
#pragma unroll
            for (int mi = 0; mi < 2; mi++)
#pragma unroll
                for (int ni = 0; ni < 4; ni++)
                    acc[mi][ni] = __builtin_amdgcn_mfma_f32_16x16x32_bf16(af[mi], bfr[ni],
                                                                         acc[mi][ni], 0, 0, 0);
        }
        const float* carr2 = carr + 2 * 256;
        float cv[4];
#pragma unroll
        for (int ni = 0; ni < 4; ni++) cv[ni] = carr2[wid * 64 + ni * 16 + l15];
#pragma unroll
        for (int mi = 0; mi < 2; mi++)
#pragma unroll
            for (int r = 0; r < 4; r++) {
                int row = mi * 16 + l4 * 4 + r;
                int nid = s_n2[row];
                float s = 0.f, s2 = 0.f;
#pragma unroll
                for (int ni = 0; ni < 4; ni++) {
                    int c = wid * 64 + ni * 16 + l15;
                    float h = fmaxf(acc[mi][ni][r] + bf2f(T0[(long)nid * 256 + c]) + cv[ni], 0.f);
                    acc[mi][ni][r] = h;
                    s += h;
                    s2 += h * h;
                }
#pragma unroll
                for (int m = 1; m < 16; m <<= 1) {
                    s += __shfl_xor(s, m);
                    s2 += __shfl_xor(s2, m);
                }
                if (l15 == 0) {
                    s_part[wid][row][0] = s;
                    s_part[wid][row][1] = s2;
                }
            }
        __syncthreads();
#pragma unroll
        for (int mi = 0; mi < 2; mi++)
#pragma unroll
            for (int r = 0; r < 4; r++) {
                int row = mi * 16 + l4 * 4 + r;
                float s = s_part[0][row][0] + s_part[1][row][0] + s_part[2][row][0] + s_part[3][row][0];
                float s2 = s_part[0][row][1] + s_part[1][row][1] + s_part[2][row][1] + s_part[3][row][1];
                float mu = s * (1.f / 256.f);
                float rs = rsqrtf(s2 * (1.f / 256.f) - mu * mu + 1e-5f);
#pragma unroll
                for (int ni = 0; ni < 4; ni++) {
                    int c = wid * 64 + ni * 16 + l15;
                    *(unsigned short*)((char*)sL2 + row * 512 +
                                       ((c * 2) ^ (((row >> 1) & 7) << 4))) =
                        f2bf((acc[mi][ni][r] - mu) * rs * gv[ni] + bv[ni]);
                }
            }
        __syncthreads();
    }

    // ---- Level 1: 16 rows
    {
        f32x4 acc[4] = {};
        for (int kk = 0; kk < 16; kk++) {
            int k0 = kk * 32 + l4 * 8;
            int hi = k0 >> 8;
            int innerk = k0 & 255;
            int binr = (k0 & 255) * 2;
            int node = 2 * l15 + hi;
            bf16x8 af = *(const bf16x8*)((const char*)sL2 + node * 512 +
                                         (binr ^ (((node >> 1) & 7) << 4)));
            const unsigned short* Wb = WTbf + (long)(256 + hi * 256) * 256;
#pragma unroll
            for (int ni = 0; ni < 4; ni++) {
                int cn = wid * 64 + ni * 16 + l15;
                bf16x8 bfr = *(const bf16x8*)(Wb + (long)cn * 256 + innerk);
                acc[ni] = __builtin_amdgcn_mfma_f32_16x16x32_bf16(af, bfr, acc[ni], 0, 0, 0);
            }
        }
        const float* carr1 = carr + 256;
        float cv[4];
#pragma unroll
        for (int ni = 0; ni < 4; ni++) cv[ni] = carr1[wid * 64 + ni * 16 + l15];
#pragma unroll
        for (int r = 0; r < 4; r++) {
            int row = l4 * 4 + r;
            int nid = s_n1[row];
            float s = 0.f, s2 = 0.f;
#pragma unroll
            for (int ni = 0; ni < 4; ni++) {
                int c = wid * 64 + ni * 16 + l15;
                float h = fmaxf(acc[ni][r] + bf2f(T0[(long)nid * 256 + c]) + cv[ni], 0.f);
                acc[ni][r] = h;
                s += h;
                s2 += h * h;
            }
#pragma unroll
            for (int m = 1; m < 16; m <<= 1) {
                s += __shfl_xor(s, m);
                s2 += __shfl_xor(s2, m);
            }
            if (l15 == 0) {
                s_part[wid][row][0] = s;
                s_part[wid][row][1] = s2;
            }
        }
        __syncthreads();
#pragma unroll
        for (int r = 0; r < 4; r++) {
            int row = l4 * 4 + r;
            float s = s_part[0][row][0] + s_part[1][row][0] + s_part[2][row][0] + s_part[3][row][0];
            float s2 = s_part[0][row][1] + s_part[1][row][1] + s_part[2][row][1] + s_part[3][row][1];
            float mu = s * (1.f / 256.f);
            float rs = rsqrtf(s2 * (1.f / 256.f) - mu * mu + 1e-5f);
#pragma unroll
            for (int ni = 0; ni < 4; ni++) {
                int c = wid * 64 + ni * 16 + l15;
                *(unsigned short*)((char*)sL1 + row * 512 +
                                   ((c * 2) ^ (((row >> 1) & 7) << 4))) =
                    f2bf((acc[ni][r] - mu) * rs * gv[ni] + bv[ni]);
            }
        }
        __syncthreads();
    }

    // ---- Level 0: 8 rows -> out
    {
        f32x4 acc[4] = {};
        for (int kk = 0; kk < 16; kk++) {
            int k0 = kk * 32 + l4 * 8;
            int hi = k0 >> 8;
            int innerk = k0 & 255;
            int binr = (k0 & 255) * 2;
            int node = 2 * (l15 & 7) + hi;
            bf16x8 af = *(const bf16x8*)((const char*)sL1 + node * 512 +
                                         (binr ^ (((node >> 1) & 7) << 4)));
            const unsigned short* Wb = WTbf + (long)(256 + hi * 256) * 256;
#pragma unroll
            for (int ni = 0; ni < 4; ni++) {
                int cn = wid * 64 + ni * 16 + l15;
                bf16x8 bfr = *(const bf16x8*)(Wb + (long)cn * 256 + innerk);
                acc[ni] = __builtin_amdgcn_mfma_f32_16x16x32_bf16(af, bfr, acc[ni], 0, 0, 0);
            }
        }
        float cv[4];
#pragma unroll
        for (int ni = 0; ni < 4; ni++) cv[ni] = carr[wid * 64 + ni * 16 + l15];
#pragma unroll
        for (int r = 0; r < 4; r++) {
            int row = l4 * 4 + r;
            int nid = s_n0[row & 7];
            float s = 0.f, s2 = 0.f;
#pragma unroll
            for (int ni = 0; ni < 4; ni++) {
                int c = wid * 64 + ni * 16 + l15;
                float h = fmaxf(acc[ni][r] + bf2f(T0[(long)nid * 256 + c]) + cv[ni], 0.f);
                acc[ni][r] = h;
                s += h;
                s2 += h * h;
            }
#pragma unroll
            for (int m = 1; m < 16; m <<= 1) {
                s += __shfl_xor(s, m);
                s2 += __shfl_xor(s2, m);
            }
            if (l15 == 0) {
                s_part[wid][row][0] = s;
                s_part[wid][row][1] = s2;
            }
        }
        __syncthreads();
#pragma unroll
        for (int r = 0; r < 4; r++) {
            int row = l4 * 4 + r;
            if (row < 8) {
                float s = s_part[0][row][0] + s_part[1][row][0] + s_part[2][row][0] + s_part[3][row][0];
                float s2 = s_part[0][row][1] + s_part[1][row][1] + s_part[2][row][1] + s_part[3][row][1];
                float mu = s * (1.f / 256.f);
                float rs = rsqrtf(s2 * (1.f / 256.f) - mu * mu + 1e-5f);
#pragma unroll
                for (int ni = 0; ni < 4; ni++) {
                    int c = wid * 64 + ni * 16 + l15;
                    out[row * 256 + c] = (acc[ni][r] - mu) * rs * gv[ni] + bv[ni];
                }
            }
        }
    }
}

extern "C" void kernel_launch(void* const* d_in, const int* in_sizes, int n_in,
                              void* d_out, int out_size, void* d_ws, size_t ws_size,
                              hipStream_t stream) {
    const int* leaf_ids = (const int*)d_in[0];
    const int* op_ids = (const int*)d_in[1];
    const float* tok = (const float*)d_in[2];
    const float* dep = (const float*)d_in[3];
    const float* idx = (const float*)d_in[4];
    const float* W = (const float*)d_in[5];
    const float* bvec = (const float*)d_in[6];
    const float* gamma = (const float*)d_in[7];
    const float* beta = (const float*)d_in[8];
    float* out = (float*)d_out;

    char* ws = (char*)d_ws;
    unsigned short* T = (unsigned short*)(ws);                            // 1.5 MB (bf16 T0|T1|T2)
    unsigned short* WTbf = (unsigned short*)(ws + 3u * 1024 * 1024);     // 384 KB
    unsigned short* tokbf = (unsigned short*)(ws + 3u * 1024 * 1024 + 512 * 1024);  // 512 KB
    float* carr = (float*)(ws + 4u * 1024 * 1024 + 64 * 1024);           // 14 KB
    float* carrp = (float*)(ws + 5u * 1024 * 1024);                      // 112 KB partials
    unsigned short* mid = (unsigned short*)(ws + 6u * 1024 * 1024);      // 32 KB (64x256 bf16)
    unsigned short* ebufA = (unsigned short*)(ws + 8u * 1024 * 1024);    // 16 MB (level-12 out)
    unsigned short* ebufB = (unsigned short*)(ws + 40u * 1024 * 1024);   // 1 MB (level-8 out)

    k_prep<<<416, 256, 0, stream>>>(tok, W, dep, idx, bvec, tokbf, WTbf, carrp);
    k_carrsum<<<14, 256, 0, stream>>>(carrp, carr);
    k_ttmm<<<dim3(32, 3), 256, 0, stream>>>(tokbf, WTbf, T);

    // levels 13+12 -> ebufA (4096 rows/batch), 32 rows/block
    k_level12f<<<dim3(128, 8), 256, 0, stream>>>(leaf_ids, op_ids, T, carr, gamma, beta, WTbf,
                                                 ebufA);
    // levels 11..8 (256 blocks: batch x 1/32 subtree) -> ebufB (level-8 out, 256 rows/batch)
    k_mid<<<256, 512, 0, stream>>>(ebufA, ebufB, op_ids, T, carr, gamma, beta, WTbf);
    // levels 7..3 (64 blocks: batch x eighth) -> mid (level-3 out, 8x256 per batch)
    k_tail<<<64, 512, 0, stream>>>(ebufB, op_ids, T, carr, gamma, beta, WTbf, mid);
    // levels 2..0
    k_root2<<<1, 256, 0, stream>>>(mid, op_ids, T, carr, gamma, beta, WTbf, out);
}